// Round 15
// baseline (1556.773 us; speedup 1.0000x reference)
//
#include <hip/hip_runtime.h>
#include <hip/hip_bf16.h>

// Problem constants: B=4, LK=512, LQ=128, D=256, H=256, L=3
// out: x [4,128,256] float32
// ROUND 15 = DIAGNOSTIC: same gru_pipe code as r14, but launched as 5 SEQUENTIAL
// grid=1 dispatches (explicit role arg) -> rocprof isolates each stage's duration
// under pipeline codegen; all fences still executed. Correct because deps are
// acyclic with full-length buffers (polls satisfied by completed prior dispatch).

typedef __attribute__((ext_vector_type(8))) short short8;
typedef __attribute__((ext_vector_type(4))) short short4_t;
typedef __attribute__((ext_vector_type(4))) float f32x4;
typedef __attribute__((ext_vector_type(4))) int i32x4;
typedef unsigned short ushort;
typedef unsigned int uint;

__device__ __forceinline__ float fast_rcp(float x) { return __builtin_amdgcn_rcpf(x); }
__device__ __forceinline__ float fast_tanh(float x) {
    float e = __expf(2.f * x);
    return 1.f - 2.f * fast_rcp(1.f + e);
}
__device__ __forceinline__ float fast_sigmoid(float x) {
    return fast_rcp(1.f + __expf(-x));
}
__device__ __forceinline__ ushort f2bf(float v) {
    unsigned int b = __builtin_bit_cast(unsigned int, v);
    unsigned int r = (b + 0x7fffu + ((b >> 16) & 1u)) >> 16;
    return (ushort)r;
}

// 8-rows-per-block GEMM. tb=0: out[row*N+n]. tb=1 (gi stream layout): row=(b*128+t)
// is remapped to out[(t*4+b)*768+n].
__global__ void gemm_rowwise8(const float* __restrict__ in, const float* __restrict__ W,
                              const float* __restrict__ bias, const float* __restrict__ bias2,
                              float* __restrict__ out, int N, int tb) {
    __shared__ float xrow[8][256];
    const int tid = threadIdx.x;
    const int row0 = blockIdx.x * 8;
#pragma unroll
    for (int r = 0; r < 8; ++r) xrow[r][tid] = in[(row0 + r) * 256 + tid];
    __syncthreads();
    for (int n = tid; n < N; n += 256) {
        const float4* wv = (const float4*)(W + n * 256);
        float s[8] = {0.f, 0.f, 0.f, 0.f, 0.f, 0.f, 0.f, 0.f};
#pragma unroll 4
        for (int k4 = 0; k4 < 64; ++k4) {
            const float4 b = wv[k4];
#pragma unroll
            for (int r = 0; r < 8; ++r) {
                const float4 a = ((const float4*)xrow[r])[k4];   // broadcast read (free)
                s[r] += a.x * b.x + a.y * b.y + a.z * b.z + a.w * b.w;
            }
        }
        float bb = 0.f;
        if (bias) bb += bias[n];
        if (bias2 && n < 512) bb += bias2[n];
#pragma unroll
        for (int r = 0; r < 8; ++r) {
            const int row = row0 + r;
            if (tb) out[((row & 127) * 4 + (row >> 7)) * 768 + n] = s[r] + bb;
            else    out[row * N + n] = s[r] + bb;
        }
    }
}

// e[b,q,k] = exp( sum_h w_v[h]*tanh(Qp[b,q,h]+Kp[b,k,h]) ); denom[q] += sum over (b,k)
__global__ void attn_scores(const float* __restrict__ Kp, const float* __restrict__ Qp,
                            const float* __restrict__ wv, float* __restrict__ e,
                            float* __restrict__ denom) {
    __shared__ float qrow[256];
    __shared__ float wvr[256];
    __shared__ float wsum[4];
    const int tid = threadIdx.x;
    const int row = blockIdx.x;      // b*128 + q
    const int b = row >> 7, q = row & 127;
    qrow[tid] = Qp[row * 256 + tid];
    wvr[tid] = wv[tid];
    __syncthreads();
    const int lane = tid & 63, w = tid >> 6;
    const float4 qv = ((const float4*)qrow)[lane];
    const float4 wvv = ((const float4*)wvr)[lane];
    float dsum = 0.f;
    for (int k = w; k < 512; k += 4) {
        const float4 kv = *(const float4*)(Kp + (b * 512 + k) * 256 + lane * 4);
        float s = fast_tanh(qv.x + kv.x) * wvv.x;
        s += fast_tanh(qv.y + kv.y) * wvv.y;
        s += fast_tanh(qv.z + kv.z) * wvv.z;
        s += fast_tanh(qv.w + kv.w) * wvv.w;
#pragma unroll
        for (int m = 1; m < 64; m <<= 1) s += __shfl_xor(s, m);
        if (lane == 0) {
            float ev = __expf(s);
            e[row * 512 + k] = ev;
            dsum += ev;
        }
    }
    if (lane == 0) wsum[w] = dsum;
    __syncthreads();
    if (tid == 0) atomicAdd(&denom[q], wsum[0] + wsum[1] + wsum[2] + wsum[3]);
}

// rep + gate + x0
__global__ void rep_gate(const float* __restrict__ e, const float* __restrict__ denom,
                         const float* __restrict__ keys, const float* __restrict__ queries,
                         const float* __restrict__ Wg, const float* __restrict__ bg,
                         float* __restrict__ x0) {
    __shared__ float att[512];
    __shared__ float urow[256];
    const int tid = threadIdx.x;
    const int row = blockIdx.x;      // b*128 + q
    const int b = row >> 7, q = row & 127;
    const float inv = 1.f / denom[q];
    att[tid] = e[row * 512 + tid] * inv;
    att[tid + 256] = e[row * 512 + 256 + tid] * inv;
    __syncthreads();
    float racc = 0.f;
#pragma unroll 4
    for (int k = 0; k < 512; ++k) racc += att[k] * keys[(b * 512 + k) * 256 + tid];
    const float u = queries[row * 256 + tid] + racc;
    urow[tid] = u;
    __syncthreads();
    const float4* uv = (const float4*)urow;
    const float4* wr = (const float4*)(Wg + tid * 256);
    float g = 0.f;
#pragma unroll 8
    for (int k4 = 0; k4 < 64; ++k4) {
        float4 a = uv[k4];
        float4 wq = wr[k4];
        g += a.x * wq.x + a.y * wq.y + a.z * wq.z + a.w * wq.w;
    }
    g += bg[tid];
    x0[row * 256 + tid] = fast_sigmoid(g) * u;
}

// Single-thread poll (r14): tid0 spins, others park at the barrier; then ALL
// threads acquire-fence. In serialized mode polls are satisfied immediately but
// the fences still run -> their cost stays inside the measured stage time.
__device__ __forceinline__ void poll_flag(const uint* cnt, uint need, int tid) {
    if (tid == 0) {
        while (atomicAdd((uint*)cnt, 0u) < need) __builtin_amdgcn_s_sleep(1);
    }
    __syncthreads();
    __threadfence();   // acquire: invalidate stale L1/L2 lines before data reads
}

// r14's gru_pipe, role now an explicit argument (grid=1 per launch this round).
// Roles: 0=W0 2=W1 4=W2 (recurrence), 1=P1 3=P2 (input projection).
// Defer-store BANNED (r9); 8-wave BANNED (r7/r8/r11).
__global__ __launch_bounds__(256, 1)
void gru_pipe(const float* __restrict__ gi0,
              float* __restrict__ gi1, float* __restrict__ gi2,
              const float* __restrict__ whh, const float* __restrict__ bhh,
              const float* __restrict__ wih, const float* __restrict__ bih,
              ushort* __restrict__ xbf0, ushort* __restrict__ xbf1,
              uint* __restrict__ flags, float* __restrict__ dout, int role) {
    __shared__ __align__(16) ushort abuf[2][32][16][8];   // 16KB (P uses abuf[0])
    __shared__ float gibuf[2][3072];                      // 24KB (W only)
    __shared__ float gbuf[3][4][256];                     // 12KB (W only)

    const int tid = threadIdx.x;
    const int lane = tid & 63, w = tid >> 6;
    const int l15 = lane & 15, lhi = lane >> 4;

    // flags padded: counter i at flags[i*32] (128B apart, distinct cachelines)
    uint* f_x0 = flags + 0;    // W0 -> P1
    uint* f_g1 = flags + 32;   // P1 -> W1
    uint* f_x1 = flags + 64;   // W1 -> P2
    uint* f_g2 = flags + 96;   // P2 -> W2

    if ((role & 1) == 0) {
        // ---------------- W role: recurrence for layer l ----------------
        const int l = role >> 1;
        const float* gi    = (l == 0) ? gi0 : (l == 1) ? gi1 : gi2;  // [128][4][768]
        const float* whh_l = whh + l * 196608;
        const float* bhh_l = bhh + l * 768;
        uint* gcnt  = (l == 1) ? f_g1 : (l == 2) ? f_g2 : nullptr;
        ushort* xbf = (l == 0) ? xbf0 : (l == 1) ? xbf1 : nullptr;   // [128][4][256] bf16
        uint* xcnt  = (l == 0) ? f_x0 : (l == 1) ? f_x1 : nullptr;

        for (int i = tid; i < 8192; i += 256) ((ushort*)abuf)[i] = 0;

        short8 bf_v[4][8];
        i32x4  bf_a[8][8];
#pragma unroll
        for (int i = 0; i < 12; ++i) {
            const int g = i >> 2, c = i & 3;
            const float* basef = whh_l + (g * 256 + w * 64 + c * 16 + l15) * 256 + lhi * 8;
#pragma unroll
            for (int ks = 0; ks < 8; ++ks) {
                const float4 a0 = *(const float4*)(basef + ks * 32);
                const float4 a1 = *(const float4*)(basef + ks * 32 + 4);
                short8 v;
                v[0] = (short)f2bf(a0.x); v[1] = (short)f2bf(a0.y);
                v[2] = (short)f2bf(a0.z); v[3] = (short)f2bf(a0.w);
                v[4] = (short)f2bf(a1.x); v[5] = (short)f2bf(a1.y);
                v[6] = (short)f2bf(a1.z); v[7] = (short)f2bf(a1.w);
                if (i < 4) bf_v[i][ks] = v;
                else       bf_a[i - 4][ks] = __builtin_bit_cast(i32x4, v);
            }
        }

        const int pb_b = lhi;
        const int pb_c = (w << 6) + (l15 << 2);
        const f32x4 bn4 = *(const f32x4*)(bhh_l + 512 + pb_c);
        float hreg[4] = {0.f, 0.f, 0.f, 0.f};

        // gi row 0 preload (granule 0 poll for l1/l2)
        if (gcnt) poll_flag(gcnt, 1u, tid);
#pragma unroll
        for (int m = 0; m < 12; ++m) gibuf[0][tid + 256 * m] = gi[tid + 256 * m];
        __syncthreads();

        for (int t = 0; t < 128; ++t) {
            // async prefetch gi row t+1; poll producer only at granule boundary
            if (t < 127) {
                if (gcnt && ((t + 1) & 3) == 0)
                    poll_flag(gcnt, (uint)(((t + 1) >> 2) + 1), tid);
#pragma unroll
                for (int m = 0; m < 12; ++m) {
                    const int jw = m * 256 + (w << 6);
                    __builtin_amdgcn_global_load_lds(
                        (const __attribute__((address_space(1))) unsigned int*)(gi + (t + 1) * 3072 + jw + lane),
                        (__attribute__((address_space(3))) unsigned int*)&gibuf[(t + 1) & 1][jw],
                        4, 0, 0);
                }
            }
            // phase A: gh = h~ @ Whh^T (reads abuf[t&1], XOR-swizzled rows)
            f32x4 acc[12];
#pragma unroll
            for (int i = 0; i < 12; ++i)
#pragma unroll
                for (int cc = 0; cc < 4; ++cc) acc[i][cc] = 0.f;
#pragma unroll
            for (int ks = 0; ks < 8; ++ks) {
                const int grp = ks * 4 + lhi;
                const short8 a = *(const short8*)&abuf[t & 1][grp][l15 ^ (grp & 15)][0];
#pragma unroll
                for (int i = 0; i < 4; ++i)
                    acc[i] = __builtin_amdgcn_mfma_f32_16x16x32_bf16(a, bf_v[i][ks], acc[i], 0, 0, 0);
#pragma unroll
                for (int i = 0; i < 8; ++i)
                    asm("v_mfma_f32_16x16x32_bf16 %0, %1, %2, %0"
                        : "+v"(acc[4 + i])
                        : "v"(a), "a"(bf_a[i][ks]));
            }
            // acc -> gbuf (wave-local; same-wave LDS ordering, r10-proven)
            if (lane < 16) {
#pragma unroll
                for (int g = 0; g < 3; ++g)
#pragma unroll
                    for (int c = 0; c < 4; ++c)
#pragma unroll
                        for (int b = 0; b < 4; ++b)
                            gbuf[g][b][(w << 6) + (c << 4) + l15] = acc[g * 4 + c][b];
            }
            // phase B
            {
                const float* gcur = gibuf[t & 1];
                const f32x4 gr = *(const f32x4*)&gbuf[0][pb_b][pb_c];
                const f32x4 gz = *(const f32x4*)&gbuf[1][pb_b][pb_c];
                const f32x4 gn = *(const f32x4*)&gbuf[2][pb_b][pb_c];
                const f32x4 ir = *(const f32x4*)&gcur[pb_b * 768 + pb_c];
                const f32x4 iz = *(const f32x4*)&gcur[pb_b * 768 + 256 + pb_c];
                const f32x4 in_ = *(const f32x4*)&gcur[pb_b * 768 + 512 + pb_c];
                f32x4 xo;
                short4_t hb;
#pragma unroll
                for (int j = 0; j < 4; ++j) {
                    const float r = fast_sigmoid(ir[j] + gr[j]);
                    const float z = fast_sigmoid(iz[j] + gz[j]);
                    const float nn = fast_tanh(in_[j] + r * (gn[j] + bn4[j]));
                    const float h2 = nn + z * (hreg[j] - nn);
                    hreg[j] = h2;
                    xo[j] = h2;
                    hb[j] = (short)f2bf(h2);
                }
                if (xbf) *(short4_t*)&xbf[t * 1024 + pb_b * 256 + pb_c] = hb;   // immediate store
                else     *(f32x4*)&dout[(pb_b * 128 + t) * 256 + pb_c] = xo;    // layer 2
                const int grp = pb_c >> 3;
                *(short4_t*)&abuf[(t + 1) & 1][grp][pb_b ^ (grp & 15)][pb_c & 7] = hb;
            }
            __syncthreads();   // abuf[t+1]+gibuf[t+1] published; all x stores drained
            // publish once per 4-step granule
            if (xcnt && (t & 3) == 3 && tid == 0) {
                __threadfence();
                atomicExch(xcnt, (uint)((t >> 2) + 1));
            }
        }
    } else {
        // ------- P role: gi_{pl}[4j..4j+3] = x_{pl-1}[granule j] @ Wih_pl^T + bias -------
        // M=16 (4 steps x 4 batches): logical A-row m = s*4 + b.
        const int pl = (role + 1) >> 1;                 // 1 or 2
        const ushort* xbf = (pl == 1) ? xbf0 : xbf1;
        uint* xcnt  = (pl == 1) ? f_x0 : f_x1;
        float* gout = (pl == 1) ? gi1 : gi2;
        uint* gcnt  = (pl == 1) ? f_g1 : f_g2;
        const float* wih_l = wih + pl * 196608;
        const float* bih_l = bih + pl * 768;
        const float* bhh_l = bhh + pl * 768;

        short8 pf_v[4][8];
        i32x4  pf_a[8][8];
        int   n12[12];
        float b12[12];
#pragma unroll
        for (int i = 0; i < 12; ++i) {
            const int g = i >> 2, c = i & 3;
            const int n = g * 256 + w * 64 + c * 16 + l15;
            n12[i] = n;
            b12[i] = bih_l[n] + (n < 512 ? bhh_l[n] : 0.f);
            const float* basef = wih_l + n * 256 + lhi * 8;
#pragma unroll
            for (int ks = 0; ks < 8; ++ks) {
                const float4 a0 = *(const float4*)(basef + ks * 32);
                const float4 a1 = *(const float4*)(basef + ks * 32 + 4);
                short8 v;
                v[0] = (short)f2bf(a0.x); v[1] = (short)f2bf(a0.y);
                v[2] = (short)f2bf(a0.z); v[3] = (short)f2bf(a0.w);
                v[4] = (short)f2bf(a1.x); v[5] = (short)f2bf(a1.y);
                v[6] = (short)f2bf(a1.z); v[7] = (short)f2bf(a1.w);
                if (i < 4) pf_v[i][ks] = v;
                else       pf_a[i - 4][ks] = __builtin_bit_cast(i32x4, v);
            }
        }
        const int pb_c = (w << 6) + (l15 << 2);
        __syncthreads();

        for (int j = 0; j < 32; ++j) {
            poll_flag(xcnt, (uint)(j + 1), tid);
            // stage granule: thread (lhi=b, pb_c) stages rows m = s*4+lhi, s=0..3
#pragma unroll
            for (int s = 0; s < 4; ++s) {
                const short4_t xv = *(const short4_t*)&xbf[(4 * j + s) * 1024 + lhi * 256 + pb_c];
                const int m = s * 4 + lhi;
                const int grp = pb_c >> 3;
                *(short4_t*)&abuf[0][grp][m ^ (grp & 15)][pb_c & 7] = xv;
            }
            __syncthreads();
            f32x4 acc[12];
#pragma unroll
            for (int i = 0; i < 12; ++i)
#pragma unroll
                for (int cc = 0; cc < 4; ++cc) acc[i][cc] = 0.f;
#pragma unroll
            for (int ks = 0; ks < 8; ++ks) {
                const int grp = ks * 4 + lhi;
                const short8 a = *(const short8*)&abuf[0][grp][l15 ^ (grp & 15)][0];
#pragma unroll
                for (int i = 0; i < 4; ++i)
                    acc[i] = __builtin_amdgcn_mfma_f32_16x16x32_bf16(a, pf_v[i][ks], acc[i], 0, 0, 0);
#pragma unroll
                for (int i = 0; i < 8; ++i)
                    asm("v_mfma_f32_16x16x32_bf16 %0, %1, %2, %0"
                        : "+v"(acc[4 + i])
                        : "v"(a), "a"(pf_a[i][ks]));
            }
            // output: lane (lhi,l15) reg r holds row m=lhi*4+r -> t=4j+lhi, batch=r
#pragma unroll
            for (int i = 0; i < 12; ++i)
#pragma unroll
                for (int b = 0; b < 4; ++b)
                    gout[(4 * j + lhi) * 3072 + b * 768 + n12[i]] = acc[i][b] + b12[i];
            __syncthreads();   // drains gout stores + all abuf reads done
            if (tid == 0) { __threadfence(); atomicExch(gcnt, (uint)(j + 1)); }
        }
    }
}

extern "C" void kernel_launch(void* const* d_in, const int* in_sizes, int n_in,
                              void* d_out, int out_size, void* d_ws, size_t ws_size,
                              hipStream_t stream) {
    (void)in_sizes; (void)n_in; (void)out_size; (void)ws_size;
    const float* keys    = (const float*)d_in[0];
    const float* queries = (const float*)d_in[1];
    const float* W_k     = (const float*)d_in[2];
    const float* W_q     = (const float*)d_in[3];
    const float* w_v     = (const float*)d_in[4];
    const float* W_g_w   = (const float*)d_in[5];
    const float* W_g_b   = (const float*)d_in[6];
    const float* Wih     = (const float*)d_in[7];
    const float* Whh     = (const float*)d_in[8];
    const float* bih     = (const float*)d_in[9];
    const float* bhh     = (const float*)d_in[10];

    float* ws = (float*)d_ws;
    float* Kp_gi0 = ws;              // 524288 (Kp; first 393216 reused as gi0)
    float* Qp    = ws + 524288;      // 131072
    float* e     = ws + 655360;      // 262144 (dead after rep_gate; overlaid by gi1)
    float* den   = ws + 917504;      // 256
    float* xA    = ws + 917760;      // 131072 (dead after gi0 gemm)
    float* gi1   = ws + 655360;      // 393216 (overlays e+den+xA, all dead by pipe time)
    float* gi2   = ws + 1048576;     // 393216
    ushort* xbf0 = (ushort*)(ws + 1441792);  // 131072 ushort
    ushort* xbf1 = (ushort*)(ws + 1507328);  // 131072 ushort
    uint*  flags = (uint*)(ws + 1572864);    // 4 counters, 128B apart (512B total)

    hipMemsetAsync((void*)den, 0, 512, stream);
    hipMemsetAsync((void*)flags, 0, 512, stream);

    gemm_rowwise8<<<256, 256, 0, stream>>>(keys, W_k, nullptr, nullptr, Kp_gi0, 256, 0);
    gemm_rowwise8<<<64, 256, 0, stream>>>(queries, W_q, nullptr, nullptr, Qp, 256, 0);
    attn_scores<<<512, 256, 0, stream>>>(Kp_gi0, Qp, w_v, e, den);
    rep_gate<<<512, 256, 0, stream>>>(e, den, keys, queries, W_g_w, W_g_b, xA);

    float* gi0 = Kp_gi0;   // Kp dead after attn_scores
    // gi0 = x0 @ Wih0^T + bih0 + bhh0_rz, in [t][b][c] stream layout
    gemm_rowwise8<<<64, 256, 0, stream>>>(xA, Wih, bih, bhh, gi0, 768, 1);

    // DIAGNOSTIC: stages serialized as separate dispatches (role explicit).
    // Correct by acyclicity; rocprof isolates each stage's duration.
    gru_pipe<<<1, 256, 0, stream>>>(gi0, gi1, gi2, Whh, bhh, Wih, bih,
                                    xbf0, xbf1, flags, (float*)d_out, 0);  // W0
    gru_pipe<<<1, 256, 0, stream>>>(gi0, gi1, gi2, Whh, bhh, Wih, bih,
                                    xbf0, xbf1, flags, (float*)d_out, 1);  // P1
    gru_pipe<<<1, 256, 0, stream>>>(gi0, gi1, gi2, Whh, bhh, Wih, bih,
                                    xbf0, xbf1, flags, (float*)d_out, 2);  // W1
    gru_pipe<<<1, 256, 0, stream>>>(gi0, gi1, gi2, Whh, bhh, Wih, bih,
                                    xbf0, xbf1, flags, (float*)d_out, 3);  // P2
    gru_pipe<<<1, 256, 0, stream>>>(gi0, gi1, gi2, Whh, bhh, Wih, bih,
                                    xbf0, xbf1, flags, (float*)d_out, 4);  // W2
}

// Round 16
// 953.127 us; speedup vs baseline: 1.6333x; 1.6333x over previous
//
#include <hip/hip_runtime.h>
#include <hip/hip_bf16.h>

// Problem constants: B=4, LK=512, LQ=128, D=256, H=256, L=3
// out: x [4,128,256] float32

typedef __attribute__((ext_vector_type(8))) short short8;
typedef __attribute__((ext_vector_type(4))) short short4_t;
typedef __attribute__((ext_vector_type(4))) float f32x4;
typedef __attribute__((ext_vector_type(4))) int i32x4;
typedef unsigned short ushort;
typedef unsigned int uint;
typedef unsigned long long u64;

__device__ __forceinline__ float fast_rcp(float x) { return __builtin_amdgcn_rcpf(x); }
__device__ __forceinline__ float fast_tanh(float x) {
    float e = __expf(2.f * x);
    return 1.f - 2.f * fast_rcp(1.f + e);
}
__device__ __forceinline__ float fast_sigmoid(float x) {
    return fast_rcp(1.f + __expf(-x));
}
__device__ __forceinline__ ushort f2bf(float v) {
    unsigned int b = __builtin_bit_cast(unsigned int, v);
    unsigned int r = (b + 0x7fffu + ((b >> 16) & 1u)) >> 16;
    return (ushort)r;
}

// 8-rows-per-block GEMM. tb=0: out[row*N+n]. tb=1 (gi stream layout): row=(b*128+t)
// is remapped to out[(t*4+b)*768+n].
__global__ void gemm_rowwise8(const float* __restrict__ in, const float* __restrict__ W,
                              const float* __restrict__ bias, const float* __restrict__ bias2,
                              float* __restrict__ out, int N, int tb) {
    __shared__ float xrow[8][256];
    const int tid = threadIdx.x;
    const int row0 = blockIdx.x * 8;
#pragma unroll
    for (int r = 0; r < 8; ++r) xrow[r][tid] = in[(row0 + r) * 256 + tid];
    __syncthreads();
    for (int n = tid; n < N; n += 256) {
        const float4* wv = (const float4*)(W + n * 256);
        float s[8] = {0.f, 0.f, 0.f, 0.f, 0.f, 0.f, 0.f, 0.f};
#pragma unroll 4
        for (int k4 = 0; k4 < 64; ++k4) {
            const float4 b = wv[k4];
#pragma unroll
            for (int r = 0; r < 8; ++r) {
                const float4 a = ((const float4*)xrow[r])[k4];   // broadcast read (free)
                s[r] += a.x * b.x + a.y * b.y + a.z * b.z + a.w * b.w;
            }
        }
        float bb = 0.f;
        if (bias) bb += bias[n];
        if (bias2 && n < 512) bb += bias2[n];
#pragma unroll
        for (int r = 0; r < 8; ++r) {
            const int row = row0 + r;
            if (tb) out[((row & 127) * 4 + (row >> 7)) * 768 + n] = s[r] + bb;
            else    out[row * N + n] = s[r] + bb;
        }
    }
}

// e[b,q,k] = exp( sum_h w_v[h]*tanh(Qp[b,q,h]+Kp[b,k,h]) ); denom[q] += sum over (b,k)
__global__ void attn_scores(const float* __restrict__ Kp, const float* __restrict__ Qp,
                            const float* __restrict__ wv, float* __restrict__ e,
                            float* __restrict__ denom) {
    __shared__ float qrow[256];
    __shared__ float wvr[256];
    __shared__ float wsum[4];
    const int tid = threadIdx.x;
    const int row = blockIdx.x;      // b*128 + q
    const int b = row >> 7, q = row & 127;
    qrow[tid] = Qp[row * 256 + tid];
    wvr[tid] = wv[tid];
    __syncthreads();
    const int lane = tid & 63, w = tid >> 6;
    const float4 qv = ((const float4*)qrow)[lane];
    const float4 wvv = ((const float4*)wvr)[lane];
    float dsum = 0.f;
    for (int k = w; k < 512; k += 4) {
        const float4 kv = *(const float4*)(Kp + (b * 512 + k) * 256 + lane * 4);
        float s = fast_tanh(qv.x + kv.x) * wvv.x;
        s += fast_tanh(qv.y + kv.y) * wvv.y;
        s += fast_tanh(qv.z + kv.z) * wvv.z;
        s += fast_tanh(qv.w + kv.w) * wvv.w;
#pragma unroll
        for (int m = 1; m < 64; m <<= 1) s += __shfl_xor(s, m);
        if (lane == 0) {
            float ev = __expf(s);
            e[row * 512 + k] = ev;
            dsum += ev;
        }
    }
    if (lane == 0) wsum[w] = dsum;
    __syncthreads();
    if (tid == 0) atomicAdd(&denom[q], wsum[0] + wsum[1] + wsum[2] + wsum[3]);
}

// rep + gate + x0
__global__ void rep_gate(const float* __restrict__ e, const float* __restrict__ denom,
                         const float* __restrict__ keys, const float* __restrict__ queries,
                         const float* __restrict__ Wg, const float* __restrict__ bg,
                         float* __restrict__ x0) {
    __shared__ float att[512];
    __shared__ float urow[256];
    const int tid = threadIdx.x;
    const int row = blockIdx.x;      // b*128 + q
    const int b = row >> 7, q = row & 127;
    const float inv = 1.f / denom[q];
    att[tid] = e[row * 512 + tid] * inv;
    att[tid + 256] = e[row * 512 + 256 + tid] * inv;
    __syncthreads();
    float racc = 0.f;
#pragma unroll 4
    for (int k = 0; k < 512; ++k) racc += att[k] * keys[(b * 512 + k) * 256 + tid];
    const float u = queries[row * 256 + tid] + racc;
    urow[tid] = u;
    __syncthreads();
    const float4* uv = (const float4*)urow;
    const float4* wr = (const float4*)(Wg + tid * 256);
    float g = 0.f;
#pragma unroll 8
    for (int k4 = 0; k4 < 64; ++k4) {
        float4 a = uv[k4];
        float4 wq = wr[k4];
        g += a.x * wq.x + a.y * wq.y + a.z * wq.z + a.w * wq.w;
    }
    g += bg[tid];
    x0[row * 256 + tid] = fast_sigmoid(g) * u;
}

// Fence-free poll: tid0 spins on the device-scope atomic, others park at the
// barrier. NO acquire fence — streams are volatile-written (write-through to
// the device coherence point) and each address is read once per replay after
// the kernel-start invalidate, so consumer caches can never hold stale copies.
// (r15 diagnostic: each per-granule fence-event cost ~2.8us AND the acquire
// buffer_inv poisoned the consumer L2, ~+90us/stage + coupling.)
__device__ __forceinline__ void poll_flag(const uint* cnt, uint need, int tid) {
    if (tid == 0) {
        while (atomicAdd((uint*)cnt, 0u) < need) __builtin_amdgcn_s_sleep(1);
    }
    __syncthreads();
}

// Layer-pipelined GRU (r14 structure, passed): GRANULE=4 publish/poll, P-roles
// M=16, grid=5 (roles: 0=W0 2=W1 4=W2 recurrence, 1=P1 3=P2 projection).
// THIS ROUND: per-granule __threadfence REMOVED on both sides; handoff streams
// (xbf0/1, gi1/2) written VOLATILE (sc0/sc1 write-through); ONE __threadfence
// at kernel start drops stale L2/L1 lines from the previous graph replay.
// Publish = syncthreads (vmcnt drained) + tid0 atomicExch (device scope).
// Defer-store BANNED (r9); 8-wave BANNED (r7/r8/r11). Acyclic deps +
// full-length buffers + 5 co-resident blocks -> deadlock-free.
__global__ __launch_bounds__(256, 1)
void gru_pipe(const float* __restrict__ gi0,
              float* __restrict__ gi1, float* __restrict__ gi2,
              const float* __restrict__ whh, const float* __restrict__ bhh,
              const float* __restrict__ wih, const float* __restrict__ bih,
              ushort* __restrict__ xbf0, ushort* __restrict__ xbf1,
              uint* __restrict__ flags, float* __restrict__ dout) {
    __shared__ __align__(16) ushort abuf[2][32][16][8];   // 16KB (P uses abuf[0])
    __shared__ float gibuf[2][3072];                      // 24KB (W only)
    __shared__ float gbuf[3][4][256];                     // 12KB (W only)

    const int role = blockIdx.x;
    const int tid = threadIdx.x;
    const int lane = tid & 63, w = tid >> 6;
    const int l15 = lane & 15, lhi = lane >> 4;

    // ONE startup fence: invalidate this CU's L1 + XCD L2 so no line cached in
    // a previous graph replay can be read stale. All stream data written this
    // replay is volatile (write-through) -> never stale after this point.
    __threadfence();

    // flags padded: counter i at flags[i*32] (128B apart, distinct cachelines)
    uint* f_x0 = flags + 0;    // W0 -> P1
    uint* f_g1 = flags + 32;   // P1 -> W1
    uint* f_x1 = flags + 64;   // W1 -> P2
    uint* f_g2 = flags + 96;   // P2 -> W2

    if ((role & 1) == 0) {
        // ---------------- W role: recurrence for layer l ----------------
        const int l = role >> 1;
        const float* gi    = (l == 0) ? gi0 : (l == 1) ? gi1 : gi2;  // [128][4][768]
        const float* whh_l = whh + l * 196608;
        const float* bhh_l = bhh + l * 768;
        uint* gcnt  = (l == 1) ? f_g1 : (l == 2) ? f_g2 : nullptr;
        ushort* xbf = (l == 0) ? xbf0 : (l == 1) ? xbf1 : nullptr;   // [128][4][256] bf16
        uint* xcnt  = (l == 0) ? f_x0 : (l == 1) ? f_x1 : nullptr;

        for (int i = tid; i < 8192; i += 256) ((ushort*)abuf)[i] = 0;

        short8 bf_v[4][8];
        i32x4  bf_a[8][8];
#pragma unroll
        for (int i = 0; i < 12; ++i) {
            const int g = i >> 2, c = i & 3;
            const float* basef = whh_l + (g * 256 + w * 64 + c * 16 + l15) * 256 + lhi * 8;
#pragma unroll
            for (int ks = 0; ks < 8; ++ks) {
                const float4 a0 = *(const float4*)(basef + ks * 32);
                const float4 a1 = *(const float4*)(basef + ks * 32 + 4);
                short8 v;
                v[0] = (short)f2bf(a0.x); v[1] = (short)f2bf(a0.y);
                v[2] = (short)f2bf(a0.z); v[3] = (short)f2bf(a0.w);
                v[4] = (short)f2bf(a1.x); v[5] = (short)f2bf(a1.y);
                v[6] = (short)f2bf(a1.z); v[7] = (short)f2bf(a1.w);
                if (i < 4) bf_v[i][ks] = v;
                else       bf_a[i - 4][ks] = __builtin_bit_cast(i32x4, v);
            }
        }

        const int pb_b = lhi;
        const int pb_c = (w << 6) + (l15 << 2);
        const f32x4 bn4 = *(const f32x4*)(bhh_l + 512 + pb_c);
        float hreg[4] = {0.f, 0.f, 0.f, 0.f};

        // gi row 0 preload (granule 0 poll for l1/l2)
        if (gcnt) poll_flag(gcnt, 1u, tid);
#pragma unroll
        for (int m = 0; m < 12; ++m) gibuf[0][tid + 256 * m] = gi[tid + 256 * m];
        __syncthreads();

        for (int t = 0; t < 128; ++t) {
            // async prefetch gi row t+1; poll producer only at granule boundary
            if (t < 127) {
                if (gcnt && ((t + 1) & 3) == 0)
                    poll_flag(gcnt, (uint)(((t + 1) >> 2) + 1), tid);
#pragma unroll
                for (int m = 0; m < 12; ++m) {
                    const int jw = m * 256 + (w << 6);
                    __builtin_amdgcn_global_load_lds(
                        (const __attribute__((address_space(1))) unsigned int*)(gi + (t + 1) * 3072 + jw + lane),
                        (__attribute__((address_space(3))) unsigned int*)&gibuf[(t + 1) & 1][jw],
                        4, 0, 0);
                }
            }
            // phase A: gh = h~ @ Whh^T (reads abuf[t&1], XOR-swizzled rows)
            f32x4 acc[12];
#pragma unroll
            for (int i = 0; i < 12; ++i)
#pragma unroll
                for (int cc = 0; cc < 4; ++cc) acc[i][cc] = 0.f;
#pragma unroll
            for (int ks = 0; ks < 8; ++ks) {
                const int grp = ks * 4 + lhi;
                const short8 a = *(const short8*)&abuf[t & 1][grp][l15 ^ (grp & 15)][0];
#pragma unroll
                for (int i = 0; i < 4; ++i)
                    acc[i] = __builtin_amdgcn_mfma_f32_16x16x32_bf16(a, bf_v[i][ks], acc[i], 0, 0, 0);
#pragma unroll
                for (int i = 0; i < 8; ++i)
                    asm("v_mfma_f32_16x16x32_bf16 %0, %1, %2, %0"
                        : "+v"(acc[4 + i])
                        : "v"(a), "a"(bf_a[i][ks]));
            }
            // acc -> gbuf (wave-local; same-wave LDS ordering, r10-proven)
            if (lane < 16) {
#pragma unroll
                for (int g = 0; g < 3; ++g)
#pragma unroll
                    for (int c = 0; c < 4; ++c)
#pragma unroll
                        for (int b = 0; b < 4; ++b)
                            gbuf[g][b][(w << 6) + (c << 4) + l15] = acc[g * 4 + c][b];
            }
            // phase B
            {
                const float* gcur = gibuf[t & 1];
                const f32x4 gr = *(const f32x4*)&gbuf[0][pb_b][pb_c];
                const f32x4 gz = *(const f32x4*)&gbuf[1][pb_b][pb_c];
                const f32x4 gn = *(const f32x4*)&gbuf[2][pb_b][pb_c];
                const f32x4 ir = *(const f32x4*)&gcur[pb_b * 768 + pb_c];
                const f32x4 iz = *(const f32x4*)&gcur[pb_b * 768 + 256 + pb_c];
                const f32x4 in_ = *(const f32x4*)&gcur[pb_b * 768 + 512 + pb_c];
                f32x4 xo;
                short4_t hb;
#pragma unroll
                for (int j = 0; j < 4; ++j) {
                    const float r = fast_sigmoid(ir[j] + gr[j]);
                    const float z = fast_sigmoid(iz[j] + gz[j]);
                    const float nn = fast_tanh(in_[j] + r * (gn[j] + bn4[j]));
                    const float h2 = nn + z * (hreg[j] - nn);
                    hreg[j] = h2;
                    xo[j] = h2;
                    hb[j] = (short)f2bf(h2);
                }
                if (xbf) {
                    // volatile (sc0/sc1 write-through) -> visible at device
                    // coherence point once vmcnt-retired; no release fence needed
                    *(volatile u64*)&xbf[t * 1024 + pb_b * 256 + pb_c] =
                        __builtin_bit_cast(u64, hb);
                } else {
                    *(f32x4*)&dout[(pb_b * 128 + t) * 256 + pb_c] = xo;    // layer 2
                }
                const int grp = pb_c >> 3;
                *(short4_t*)&abuf[(t + 1) & 1][grp][pb_b ^ (grp & 15)][pb_c & 7] = hb;
            }
            __syncthreads();   // abuf[t+1]+gibuf[t+1] published; all x stores drained
            // publish once per 4-step granule (no fence: syncthreads drained vmcnt,
            // volatile stores are already at the coherence point)
            if (xcnt && (t & 3) == 3 && tid == 0)
                atomicExch(xcnt, (uint)((t >> 2) + 1));
        }
    } else {
        // ------- P role: gi_{pl}[4j..4j+3] = x_{pl-1}[granule j] @ Wih_pl^T + bias -------
        // M=16 (4 steps x 4 batches): logical A-row m = s*4 + b.
        const int pl = (role + 1) >> 1;                 // 1 or 2
        const ushort* xbf = (pl == 1) ? xbf0 : xbf1;
        uint* xcnt  = (pl == 1) ? f_x0 : f_x1;
        float* gout = (pl == 1) ? gi1 : gi2;
        uint* gcnt  = (pl == 1) ? f_g1 : f_g2;
        const float* wih_l = wih + pl * 196608;
        const float* bih_l = bih + pl * 768;
        const float* bhh_l = bhh + pl * 768;

        short8 pf_v[4][8];
        i32x4  pf_a[8][8];
        int   n12[12];
        float b12[12];
#pragma unroll
        for (int i = 0; i < 12; ++i) {
            const int g = i >> 2, c = i & 3;
            const int n = g * 256 + w * 64 + c * 16 + l15;
            n12[i] = n;
            b12[i] = bih_l[n] + (n < 512 ? bhh_l[n] : 0.f);
            const float* basef = wih_l + n * 256 + lhi * 8;
#pragma unroll
            for (int ks = 0; ks < 8; ++ks) {
                const float4 a0 = *(const float4*)(basef + ks * 32);
                const float4 a1 = *(const float4*)(basef + ks * 32 + 4);
                short8 v;
                v[0] = (short)f2bf(a0.x); v[1] = (short)f2bf(a0.y);
                v[2] = (short)f2bf(a0.z); v[3] = (short)f2bf(a0.w);
                v[4] = (short)f2bf(a1.x); v[5] = (short)f2bf(a1.y);
                v[6] = (short)f2bf(a1.z); v[7] = (short)f2bf(a1.w);
                if (i < 4) pf_v[i][ks] = v;
                else       pf_a[i - 4][ks] = __builtin_bit_cast(i32x4, v);
            }
        }
        const int pb_c = (w << 6) + (l15 << 2);
        __syncthreads();

        for (int j = 0; j < 32; ++j) {
            poll_flag(xcnt, (uint)(j + 1), tid);
            // stage granule: thread (lhi=b, pb_c) stages rows m = s*4+lhi, s=0..3
#pragma unroll
            for (int s = 0; s < 4; ++s) {
                const short4_t xv = *(const short4_t*)&xbf[(4 * j + s) * 1024 + lhi * 256 + pb_c];
                const int m = s * 4 + lhi;
                const int grp = pb_c >> 3;
                *(short4_t*)&abuf[0][grp][m ^ (grp & 15)][pb_c & 7] = xv;
            }
            __syncthreads();
            f32x4 acc[12];
#pragma unroll
            for (int i = 0; i < 12; ++i)
#pragma unroll
                for (int cc = 0; cc < 4; ++cc) acc[i][cc] = 0.f;
#pragma unroll
            for (int ks = 0; ks < 8; ++ks) {
                const int grp = ks * 4 + lhi;
                const short8 a = *(const short8*)&abuf[0][grp][l15 ^ (grp & 15)][0];
#pragma unroll
                for (int i = 0; i < 4; ++i)
                    acc[i] = __builtin_amdgcn_mfma_f32_16x16x32_bf16(a, pf_v[i][ks], acc[i], 0, 0, 0);
#pragma unroll
                for (int i = 0; i < 8; ++i)
                    asm("v_mfma_f32_16x16x32_bf16 %0, %1, %2, %0"
                        : "+v"(acc[4 + i])
                        : "v"(a), "a"(pf_a[i][ks]));
            }
            // output: lane (lhi,l15) reg r holds row m=lhi*4+r -> t=4j+lhi, batch=r
            // volatile write-through: consumer reads without any fence
#pragma unroll
            for (int i = 0; i < 12; ++i)
#pragma unroll
                for (int b = 0; b < 4; ++b)
                    ((volatile float*)gout)[(4 * j + lhi) * 3072 + b * 768 + n12[i]] = acc[i][b] + b12[i];
            __syncthreads();   // drains gout stores + all abuf reads done
            if (tid == 0) atomicExch(gcnt, (uint)(j + 1));
        }
    }
}

extern "C" void kernel_launch(void* const* d_in, const int* in_sizes, int n_in,
                              void* d_out, int out_size, void* d_ws, size_t ws_size,
                              hipStream_t stream) {
    (void)in_sizes; (void)n_in; (void)out_size; (void)ws_size;
    const float* keys    = (const float*)d_in[0];
    const float* queries = (const float*)d_in[1];
    const float* W_k     = (const float*)d_in[2];
    const float* W_q     = (const float*)d_in[3];
    const float* w_v     = (const float*)d_in[4];
    const float* W_g_w   = (const float*)d_in[5];
    const float* W_g_b   = (const float*)d_in[6];
    const float* Wih     = (const float*)d_in[7];
    const float* Whh     = (const float*)d_in[8];
    const float* bih     = (const float*)d_in[9];
    const float* bhh     = (const float*)d_in[10];

    float* ws = (float*)d_ws;
    float* Kp_gi0 = ws;              // 524288 (Kp; first 393216 reused as gi0)
    float* Qp    = ws + 524288;      // 131072
    float* e     = ws + 655360;      // 262144 (dead after rep_gate; overlaid by gi1)
    float* den   = ws + 917504;      // 256
    float* xA    = ws + 917760;      // 131072 (dead after gi0 gemm)
    float* gi1   = ws + 655360;      // 393216 (overlays e+den+xA, all dead by pipe time)
    float* gi2   = ws + 1048576;     // 393216
    ushort* xbf0 = (ushort*)(ws + 1441792);  // 131072 ushort
    ushort* xbf1 = (ushort*)(ws + 1507328);  // 131072 ushort
    uint*  flags = (uint*)(ws + 1572864);    // 4 counters, 128B apart (512B total)

    hipMemsetAsync((void*)den, 0, 512, stream);
    hipMemsetAsync((void*)flags, 0, 512, stream);

    gemm_rowwise8<<<256, 256, 0, stream>>>(keys, W_k, nullptr, nullptr, Kp_gi0, 256, 0);
    gemm_rowwise8<<<64, 256, 0, stream>>>(queries, W_q, nullptr, nullptr, Qp, 256, 0);
    attn_scores<<<512, 256, 0, stream>>>(Kp_gi0, Qp, w_v, e, den);
    rep_gate<<<512, 256, 0, stream>>>(e, den, keys, queries, W_g_w, W_g_b, xA);

    float* gi0 = Kp_gi0;   // Kp dead after attn_scores
    // gi0 = x0 @ Wih0^T + bih0 + bhh0_rz, in [t][b][c] stream layout
    gemm_rowwise8<<<64, 256, 0, stream>>>(xA, Wih, bih, bhh, gi0, 768, 1);

    gru_pipe<<<5, 256, 0, stream>>>(gi0, gi1, gi2, Whh, bhh, Wih, bih,
                                    xbf0, xbf1, flags, (float*)d_out);
}

// Round 18
// 711.251 us; speedup vs baseline: 2.1888x; 1.3401x over previous
//
#include <hip/hip_runtime.h>
#include <hip/hip_bf16.h>

// Problem constants: B=4, LK=512, LQ=128, D=256, H=256, L=3
// out: x [4,128,256] float32
// ROUND 18 = consolidation: byte-identical resubmission of r14 (best passing,
// 708us). Banned by experiment: defer-store (r9 NaN), 8-wave gru (r7/r8/r11
// 3.3e-2), volatile write-through streams (r16 -245us), granule>4 (r17 NaN).

typedef __attribute__((ext_vector_type(8))) short short8;
typedef __attribute__((ext_vector_type(4))) short short4_t;
typedef __attribute__((ext_vector_type(4))) float f32x4;
typedef __attribute__((ext_vector_type(4))) int i32x4;
typedef unsigned short ushort;
typedef unsigned int uint;

__device__ __forceinline__ float fast_rcp(float x) { return __builtin_amdgcn_rcpf(x); }
__device__ __forceinline__ float fast_tanh(float x) {
    float e = __expf(2.f * x);
    return 1.f - 2.f * fast_rcp(1.f + e);
}
__device__ __forceinline__ float fast_sigmoid(float x) {
    return fast_rcp(1.f + __expf(-x));
}
__device__ __forceinline__ ushort f2bf(float v) {
    unsigned int b = __builtin_bit_cast(unsigned int, v);
    unsigned int r = (b + 0x7fffu + ((b >> 16) & 1u)) >> 16;
    return (ushort)r;
}

// 8-rows-per-block GEMM. tb=0: out[row*N+n]. tb=1 (gi stream layout): row=(b*128+t)
// is remapped to out[(t*4+b)*768+n].
__global__ void gemm_rowwise8(const float* __restrict__ in, const float* __restrict__ W,
                              const float* __restrict__ bias, const float* __restrict__ bias2,
                              float* __restrict__ out, int N, int tb) {
    __shared__ float xrow[8][256];
    const int tid = threadIdx.x;
    const int row0 = blockIdx.x * 8;
#pragma unroll
    for (int r = 0; r < 8; ++r) xrow[r][tid] = in[(row0 + r) * 256 + tid];
    __syncthreads();
    for (int n = tid; n < N; n += 256) {
        const float4* wv = (const float4*)(W + n * 256);
        float s[8] = {0.f, 0.f, 0.f, 0.f, 0.f, 0.f, 0.f, 0.f};
#pragma unroll 4
        for (int k4 = 0; k4 < 64; ++k4) {
            const float4 b = wv[k4];
#pragma unroll
            for (int r = 0; r < 8; ++r) {
                const float4 a = ((const float4*)xrow[r])[k4];   // broadcast read (free)
                s[r] += a.x * b.x + a.y * b.y + a.z * b.z + a.w * b.w;
            }
        }
        float bb = 0.f;
        if (bias) bb += bias[n];
        if (bias2 && n < 512) bb += bias2[n];
#pragma unroll
        for (int r = 0; r < 8; ++r) {
            const int row = row0 + r;
            if (tb) out[((row & 127) * 4 + (row >> 7)) * 768 + n] = s[r] + bb;
            else    out[row * N + n] = s[r] + bb;
        }
    }
}

// e[b,q,k] = exp( sum_h w_v[h]*tanh(Qp[b,q,h]+Kp[b,k,h]) ); denom[q] += sum over (b,k)
__global__ void attn_scores(const float* __restrict__ Kp, const float* __restrict__ Qp,
                            const float* __restrict__ wv, float* __restrict__ e,
                            float* __restrict__ denom) {
    __shared__ float qrow[256];
    __shared__ float wvr[256];
    __shared__ float wsum[4];
    const int tid = threadIdx.x;
    const int row = blockIdx.x;      // b*128 + q
    const int b = row >> 7, q = row & 127;
    qrow[tid] = Qp[row * 256 + tid];
    wvr[tid] = wv[tid];
    __syncthreads();
    const int lane = tid & 63, w = tid >> 6;
    const float4 qv = ((const float4*)qrow)[lane];
    const float4 wvv = ((const float4*)wvr)[lane];
    float dsum = 0.f;
    for (int k = w; k < 512; k += 4) {
        const float4 kv = *(const float4*)(Kp + (b * 512 + k) * 256 + lane * 4);
        float s = fast_tanh(qv.x + kv.x) * wvv.x;
        s += fast_tanh(qv.y + kv.y) * wvv.y;
        s += fast_tanh(qv.z + kv.z) * wvv.z;
        s += fast_tanh(qv.w + kv.w) * wvv.w;
#pragma unroll
        for (int m = 1; m < 64; m <<= 1) s += __shfl_xor(s, m);
        if (lane == 0) {
            float ev = __expf(s);
            e[row * 512 + k] = ev;
            dsum += ev;
        }
    }
    if (lane == 0) wsum[w] = dsum;
    __syncthreads();
    if (tid == 0) atomicAdd(&denom[q], wsum[0] + wsum[1] + wsum[2] + wsum[3]);
}

// rep + gate + x0
__global__ void rep_gate(const float* __restrict__ e, const float* __restrict__ denom,
                         const float* __restrict__ keys, const float* __restrict__ queries,
                         const float* __restrict__ Wg, const float* __restrict__ bg,
                         float* __restrict__ x0) {
    __shared__ float att[512];
    __shared__ float urow[256];
    const int tid = threadIdx.x;
    const int row = blockIdx.x;      // b*128 + q
    const int b = row >> 7, q = row & 127;
    const float inv = 1.f / denom[q];
    att[tid] = e[row * 512 + tid] * inv;
    att[tid + 256] = e[row * 512 + 256 + tid] * inv;
    __syncthreads();
    float racc = 0.f;
#pragma unroll 4
    for (int k = 0; k < 512; ++k) racc += att[k] * keys[(b * 512 + k) * 256 + tid];
    const float u = queries[row * 256 + tid] + racc;
    urow[tid] = u;
    __syncthreads();
    const float4* uv = (const float4*)urow;
    const float4* wr = (const float4*)(Wg + tid * 256);
    float g = 0.f;
#pragma unroll 8
    for (int k4 = 0; k4 < 64; ++k4) {
        float4 a = uv[k4];
        float4 wq = wr[k4];
        g += a.x * wq.x + a.y * wq.y + a.z * wq.z + a.w * wq.w;
    }
    g += bg[tid];
    x0[row * 256 + tid] = fast_sigmoid(g) * u;
}

// Single-thread poll: tid0 spins on the flag, everyone else parks at the
// barrier; then ALL threads acquire-fence.
__device__ __forceinline__ void poll_flag(const uint* cnt, uint need, int tid) {
    if (tid == 0) {
        while (atomicAdd((uint*)cnt, 0u) < need) __builtin_amdgcn_s_sleep(1);
    }
    __syncthreads();
    __threadfence();   // acquire: invalidate stale L1/L2 lines before data reads
}

// Layer-pipelined GRU (r13/r14-proven): GRANULE=4 publish/poll, P-roles M=16.
// Flags padded 128B apart + single-thread poll. Roles: 0=W0 2=W1 4=W2, 1=P1 3=P2.
// Acyclic deps + full-length buffers -> deadlock-free under any scheduling.
__global__ __launch_bounds__(256, 1)
void gru_pipe(const float* __restrict__ gi0,
              float* __restrict__ gi1, float* __restrict__ gi2,
              const float* __restrict__ whh, const float* __restrict__ bhh,
              const float* __restrict__ wih, const float* __restrict__ bih,
              ushort* __restrict__ xbf0, ushort* __restrict__ xbf1,
              uint* __restrict__ flags, float* __restrict__ dout) {
    __shared__ __align__(16) ushort abuf[2][32][16][8];   // 16KB (P uses abuf[0])
    __shared__ float gibuf[2][3072];                      // 24KB (W only)
    __shared__ float gbuf[3][4][256];                     // 12KB (W only)

    const int role = blockIdx.x;
    const int tid = threadIdx.x;
    const int lane = tid & 63, w = tid >> 6;
    const int l15 = lane & 15, lhi = lane >> 4;

    // flags padded: counter i at flags[i*32] (128B apart, distinct cachelines)
    uint* f_x0 = flags + 0;    // W0 -> P1
    uint* f_g1 = flags + 32;   // P1 -> W1
    uint* f_x1 = flags + 64;   // W1 -> P2
    uint* f_g2 = flags + 96;   // P2 -> W2

    if ((role & 1) == 0) {
        // ---------------- W role: recurrence for layer l ----------------
        const int l = role >> 1;
        const float* gi    = (l == 0) ? gi0 : (l == 1) ? gi1 : gi2;  // [128][4][768]
        const float* whh_l = whh + l * 196608;
        const float* bhh_l = bhh + l * 768;
        uint* gcnt  = (l == 1) ? f_g1 : (l == 2) ? f_g2 : nullptr;
        ushort* xbf = (l == 0) ? xbf0 : (l == 1) ? xbf1 : nullptr;   // [128][4][256] bf16
        uint* xcnt  = (l == 0) ? f_x0 : (l == 1) ? f_x1 : nullptr;

        for (int i = tid; i < 8192; i += 256) ((ushort*)abuf)[i] = 0;

        short8 bf_v[4][8];
        i32x4  bf_a[8][8];
#pragma unroll
        for (int i = 0; i < 12; ++i) {
            const int g = i >> 2, c = i & 3;
            const float* basef = whh_l + (g * 256 + w * 64 + c * 16 + l15) * 256 + lhi * 8;
#pragma unroll
            for (int ks = 0; ks < 8; ++ks) {
                const float4 a0 = *(const float4*)(basef + ks * 32);
                const float4 a1 = *(const float4*)(basef + ks * 32 + 4);
                short8 v;
                v[0] = (short)f2bf(a0.x); v[1] = (short)f2bf(a0.y);
                v[2] = (short)f2bf(a0.z); v[3] = (short)f2bf(a0.w);
                v[4] = (short)f2bf(a1.x); v[5] = (short)f2bf(a1.y);
                v[6] = (short)f2bf(a1.z); v[7] = (short)f2bf(a1.w);
                if (i < 4) bf_v[i][ks] = v;
                else       bf_a[i - 4][ks] = __builtin_bit_cast(i32x4, v);
            }
        }

        const int pb_b = lhi;
        const int pb_c = (w << 6) + (l15 << 2);
        const f32x4 bn4 = *(const f32x4*)(bhh_l + 512 + pb_c);
        float hreg[4] = {0.f, 0.f, 0.f, 0.f};

        // gi row 0 preload (granule 0 poll for l1/l2)
        if (gcnt) poll_flag(gcnt, 1u, tid);
#pragma unroll
        for (int m = 0; m < 12; ++m) gibuf[0][tid + 256 * m] = gi[tid + 256 * m];
        __syncthreads();

        for (int t = 0; t < 128; ++t) {
            // async prefetch gi row t+1; poll producer only at granule boundary
            if (t < 127) {
                if (gcnt && ((t + 1) & 3) == 0)
                    poll_flag(gcnt, (uint)(((t + 1) >> 2) + 1), tid);
#pragma unroll
                for (int m = 0; m < 12; ++m) {
                    const int jw = m * 256 + (w << 6);
                    __builtin_amdgcn_global_load_lds(
                        (const __attribute__((address_space(1))) unsigned int*)(gi + (t + 1) * 3072 + jw + lane),
                        (__attribute__((address_space(3))) unsigned int*)&gibuf[(t + 1) & 1][jw],
                        4, 0, 0);
                }
            }
            // phase A: gh = h~ @ Whh^T (reads abuf[t&1], XOR-swizzled rows)
            f32x4 acc[12];
#pragma unroll
            for (int i = 0; i < 12; ++i)
#pragma unroll
                for (int cc = 0; cc < 4; ++cc) acc[i][cc] = 0.f;
#pragma unroll
            for (int ks = 0; ks < 8; ++ks) {
                const int grp = ks * 4 + lhi;
                const short8 a = *(const short8*)&abuf[t & 1][grp][l15 ^ (grp & 15)][0];
#pragma unroll
                for (int i = 0; i < 4; ++i)
                    acc[i] = __builtin_amdgcn_mfma_f32_16x16x32_bf16(a, bf_v[i][ks], acc[i], 0, 0, 0);
#pragma unroll
                for (int i = 0; i < 8; ++i)
                    asm("v_mfma_f32_16x16x32_bf16 %0, %1, %2, %0"
                        : "+v"(acc[4 + i])
                        : "v"(a), "a"(bf_a[i][ks]));
            }
            // acc -> gbuf (wave-local; same-wave LDS ordering, r10-proven)
            if (lane < 16) {
#pragma unroll
                for (int g = 0; g < 3; ++g)
#pragma unroll
                    for (int c = 0; c < 4; ++c)
#pragma unroll
                        for (int b = 0; b < 4; ++b)
                            gbuf[g][b][(w << 6) + (c << 4) + l15] = acc[g * 4 + c][b];
            }
            // phase B
            {
                const float* gcur = gibuf[t & 1];
                const f32x4 gr = *(const f32x4*)&gbuf[0][pb_b][pb_c];
                const f32x4 gz = *(const f32x4*)&gbuf[1][pb_b][pb_c];
                const f32x4 gn = *(const f32x4*)&gbuf[2][pb_b][pb_c];
                const f32x4 ir = *(const f32x4*)&gcur[pb_b * 768 + pb_c];
                const f32x4 iz = *(const f32x4*)&gcur[pb_b * 768 + 256 + pb_c];
                const f32x4 in_ = *(const f32x4*)&gcur[pb_b * 768 + 512 + pb_c];
                f32x4 xo;
                short4_t hb;
#pragma unroll
                for (int j = 0; j < 4; ++j) {
                    const float r = fast_sigmoid(ir[j] + gr[j]);
                    const float z = fast_sigmoid(iz[j] + gz[j]);
                    const float nn = fast_tanh(in_[j] + r * (gn[j] + bn4[j]));
                    const float h2 = nn + z * (hreg[j] - nn);
                    hreg[j] = h2;
                    xo[j] = h2;
                    hb[j] = (short)f2bf(h2);
                }
                if (xbf) *(short4_t*)&xbf[t * 1024 + pb_b * 256 + pb_c] = hb;   // immediate store
                else     *(f32x4*)&dout[(pb_b * 128 + t) * 256 + pb_c] = xo;    // layer 2
                const int grp = pb_c >> 3;
                *(short4_t*)&abuf[(t + 1) & 1][grp][pb_b ^ (grp & 15)][pb_c & 7] = hb;
            }
            __syncthreads();   // abuf[t+1]+gibuf[t+1] published; all x stores drained
            // publish once per 4-step granule
            if (xcnt && (t & 3) == 3 && tid == 0) {
                __threadfence();
                atomicExch(xcnt, (uint)((t >> 2) + 1));
            }
        }
    } else {
        // ------- P role: gi_{pl}[4j..4j+3] = x_{pl-1}[granule j] @ Wih_pl^T + bias -------
        // M=16 (4 steps x 4 batches): logical A-row m = s*4 + b.
        const int pl = (role + 1) >> 1;                 // 1 or 2
        const ushort* xbf = (pl == 1) ? xbf0 : xbf1;
        uint* xcnt  = (pl == 1) ? f_x0 : f_x1;
        float* gout = (pl == 1) ? gi1 : gi2;
        uint* gcnt  = (pl == 1) ? f_g1 : f_g2;
        const float* wih_l = wih + pl * 196608;
        const float* bih_l = bih + pl * 768;
        const float* bhh_l = bhh + pl * 768;

        short8 pf_v[4][8];
        i32x4  pf_a[8][8];
        int   n12[12];
        float b12[12];
#pragma unroll
        for (int i = 0; i < 12; ++i) {
            const int g = i >> 2, c = i & 3;
            const int n = g * 256 + w * 64 + c * 16 + l15;
            n12[i] = n;
            b12[i] = bih_l[n] + (n < 512 ? bhh_l[n] : 0.f);
            const float* basef = wih_l + n * 256 + lhi * 8;
#pragma unroll
            for (int ks = 0; ks < 8; ++ks) {
                const float4 a0 = *(const float4*)(basef + ks * 32);
                const float4 a1 = *(const float4*)(basef + ks * 32 + 4);
                short8 v;
                v[0] = (short)f2bf(a0.x); v[1] = (short)f2bf(a0.y);
                v[2] = (short)f2bf(a0.z); v[3] = (short)f2bf(a0.w);
                v[4] = (short)f2bf(a1.x); v[5] = (short)f2bf(a1.y);
                v[6] = (short)f2bf(a1.z); v[7] = (short)f2bf(a1.w);
                if (i < 4) pf_v[i][ks] = v;
                else       pf_a[i - 4][ks] = __builtin_bit_cast(i32x4, v);
            }
        }
        const int pb_c = (w << 6) + (l15 << 2);
        __syncthreads();

        for (int j = 0; j < 32; ++j) {
            poll_flag(xcnt, (uint)(j + 1), tid);
            // stage granule: thread (lhi=b, pb_c) stages rows m = s*4+lhi, s=0..3
#pragma unroll
            for (int s = 0; s < 4; ++s) {
                const short4_t xv = *(const short4_t*)&xbf[(4 * j + s) * 1024 + lhi * 256 + pb_c];
                const int m = s * 4 + lhi;
                const int grp = pb_c >> 3;
                *(short4_t*)&abuf[0][grp][m ^ (grp & 15)][pb_c & 7] = xv;
            }
            __syncthreads();
            f32x4 acc[12];
#pragma unroll
            for (int i = 0; i < 12; ++i)
#pragma unroll
                for (int cc = 0; cc < 4; ++cc) acc[i][cc] = 0.f;
#pragma unroll
            for (int ks = 0; ks < 8; ++ks) {
                const int grp = ks * 4 + lhi;
                const short8 a = *(const short8*)&abuf[0][grp][l15 ^ (grp & 15)][0];
#pragma unroll
                for (int i = 0; i < 4; ++i)
                    acc[i] = __builtin_amdgcn_mfma_f32_16x16x32_bf16(a, pf_v[i][ks], acc[i], 0, 0, 0);
#pragma unroll
                for (int i = 0; i < 8; ++i)
                    asm("v_mfma_f32_16x16x32_bf16 %0, %1, %2, %0"
                        : "+v"(acc[4 + i])
                        : "v"(a), "a"(pf_a[i][ks]));
            }
            // output: lane (lhi,l15) reg r holds row m=lhi*4+r -> t=4j+lhi, batch=r
#pragma unroll
            for (int i = 0; i < 12; ++i)
#pragma unroll
                for (int b = 0; b < 4; ++b)
                    gout[(4 * j + lhi) * 3072 + b * 768 + n12[i]] = acc[i][b] + b12[i];
            __syncthreads();   // drains gout stores + all abuf reads done
            if (tid == 0) { __threadfence(); atomicExch(gcnt, (uint)(j + 1)); }
        }
    }
}

extern "C" void kernel_launch(void* const* d_in, const int* in_sizes, int n_in,
                              void* d_out, int out_size, void* d_ws, size_t ws_size,
                              hipStream_t stream) {
    (void)in_sizes; (void)n_in; (void)out_size; (void)ws_size;
    const float* keys    = (const float*)d_in[0];
    const float* queries = (const float*)d_in[1];
    const float* W_k     = (const float*)d_in[2];
    const float* W_q     = (const float*)d_in[3];
    const float* w_v     = (const float*)d_in[4];
    const float* W_g_w   = (const float*)d_in[5];
    const float* W_g_b   = (const float*)d_in[6];
    const float* Wih     = (const float*)d_in[7];
    const float* Whh     = (const float*)d_in[8];
    const float* bih     = (const float*)d_in[9];
    const float* bhh     = (const float*)d_in[10];

    float* ws = (float*)d_ws;
    float* Kp_gi0 = ws;              // 524288 (Kp; first 393216 reused as gi0)
    float* Qp    = ws + 524288;      // 131072
    float* e     = ws + 655360;      // 262144 (dead after rep_gate; overlaid by gi1)
    float* den   = ws + 917504;      // 256
    float* xA    = ws + 917760;      // 131072 (dead after gi0 gemm)
    float* gi1   = ws + 655360;      // 393216 (overlays e+den+xA, all dead by pipe time)
    float* gi2   = ws + 1048576;     // 393216
    ushort* xbf0 = (ushort*)(ws + 1441792);  // 131072 ushort
    ushort* xbf1 = (ushort*)(ws + 1507328);  // 131072 ushort
    uint*  flags = (uint*)(ws + 1572864);    // 4 counters, 128B apart (512B total)

    hipMemsetAsync((void*)den, 0, 512, stream);
    hipMemsetAsync((void*)flags, 0, 512, stream);

    gemm_rowwise8<<<256, 256, 0, stream>>>(keys, W_k, nullptr, nullptr, Kp_gi0, 256, 0);
    gemm_rowwise8<<<64, 256, 0, stream>>>(queries, W_q, nullptr, nullptr, Qp, 256, 0);
    attn_scores<<<512, 256, 0, stream>>>(Kp_gi0, Qp, w_v, e, den);
    rep_gate<<<512, 256, 0, stream>>>(e, den, keys, queries, W_g_w, W_g_b, xA);

    float* gi0 = Kp_gi0;   // Kp dead after attn_scores
    // gi0 = x0 @ Wih0^T + bih0 + bhh0_rz, in [t][b][c] stream layout
    gemm_rowwise8<<<64, 256, 0, stream>>>(xA, Wih, bih, bhh, gi0, 768, 1);

    gru_pipe<<<5, 256, 0, stream>>>(gi0, gi1, gi2, Whh, bhh, Wih, bih,
                                    xbf0, xbf1, flags, (float*)d_out);
}

// Round 19
// 684.639 us; speedup vs baseline: 2.2739x; 1.0389x over previous
//
#include <hip/hip_runtime.h>
#include <hip/hip_bf16.h>

// Problem constants: B=4, LK=512, LQ=128, D=256, H=256, L=3
// out: x [4,128,256] float32
// ROUND 19 = r18 + ONE change: W-roles publish xbf via VOLATILE 8B stores
// (write-through to device coherence point; r16-proven correct) and drop their
// per-granule release __threadfence (~2.8us/event, 32 events/stage — r15).
// P-roles unchanged (regular stores + release fence: r16 showed volatile
// scalar-store storm regresses). ALL consumer acquire fences retained.
// Banned: defer-store (r9 NaN), 8-wave gru (r7/r8/r11), granule>4 (r17 NaN),
// volatile P-stores (r16 -245us).

typedef __attribute__((ext_vector_type(8))) short short8;
typedef __attribute__((ext_vector_type(4))) short short4_t;
typedef __attribute__((ext_vector_type(4))) float f32x4;
typedef __attribute__((ext_vector_type(4))) int i32x4;
typedef unsigned short ushort;
typedef unsigned int uint;
typedef unsigned long long u64;

__device__ __forceinline__ float fast_rcp(float x) { return __builtin_amdgcn_rcpf(x); }
__device__ __forceinline__ float fast_tanh(float x) {
    float e = __expf(2.f * x);
    return 1.f - 2.f * fast_rcp(1.f + e);
}
__device__ __forceinline__ float fast_sigmoid(float x) {
    return fast_rcp(1.f + __expf(-x));
}
__device__ __forceinline__ ushort f2bf(float v) {
    unsigned int b = __builtin_bit_cast(unsigned int, v);
    unsigned int r = (b + 0x7fffu + ((b >> 16) & 1u)) >> 16;
    return (ushort)r;
}

// 8-rows-per-block GEMM. tb=0: out[row*N+n]. tb=1 (gi stream layout): row=(b*128+t)
// is remapped to out[(t*4+b)*768+n].
__global__ void gemm_rowwise8(const float* __restrict__ in, const float* __restrict__ W,
                              const float* __restrict__ bias, const float* __restrict__ bias2,
                              float* __restrict__ out, int N, int tb) {
    __shared__ float xrow[8][256];
    const int tid = threadIdx.x;
    const int row0 = blockIdx.x * 8;
#pragma unroll
    for (int r = 0; r < 8; ++r) xrow[r][tid] = in[(row0 + r) * 256 + tid];
    __syncthreads();
    for (int n = tid; n < N; n += 256) {
        const float4* wv = (const float4*)(W + n * 256);
        float s[8] = {0.f, 0.f, 0.f, 0.f, 0.f, 0.f, 0.f, 0.f};
#pragma unroll 4
        for (int k4 = 0; k4 < 64; ++k4) {
            const float4 b = wv[k4];
#pragma unroll
            for (int r = 0; r < 8; ++r) {
                const float4 a = ((const float4*)xrow[r])[k4];   // broadcast read (free)
                s[r] += a.x * b.x + a.y * b.y + a.z * b.z + a.w * b.w;
            }
        }
        float bb = 0.f;
        if (bias) bb += bias[n];
        if (bias2 && n < 512) bb += bias2[n];
#pragma unroll
        for (int r = 0; r < 8; ++r) {
            const int row = row0 + r;
            if (tb) out[((row & 127) * 4 + (row >> 7)) * 768 + n] = s[r] + bb;
            else    out[row * N + n] = s[r] + bb;
        }
    }
}

// e[b,q,k] = exp( sum_h w_v[h]*tanh(Qp[b,q,h]+Kp[b,k,h]) ); denom[q] += sum over (b,k)
__global__ void attn_scores(const float* __restrict__ Kp, const float* __restrict__ Qp,
                            const float* __restrict__ wv, float* __restrict__ e,
                            float* __restrict__ denom) {
    __shared__ float qrow[256];
    __shared__ float wvr[256];
    __shared__ float wsum[4];
    const int tid = threadIdx.x;
    const int row = blockIdx.x;      // b*128 + q
    const int b = row >> 7, q = row & 127;
    qrow[tid] = Qp[row * 256 + tid];
    wvr[tid] = wv[tid];
    __syncthreads();
    const int lane = tid & 63, w = tid >> 6;
    const float4 qv = ((const float4*)qrow)[lane];
    const float4 wvv = ((const float4*)wvr)[lane];
    float dsum = 0.f;
    for (int k = w; k < 512; k += 4) {
        const float4 kv = *(const float4*)(Kp + (b * 512 + k) * 256 + lane * 4);
        float s = fast_tanh(qv.x + kv.x) * wvv.x;
        s += fast_tanh(qv.y + kv.y) * wvv.y;
        s += fast_tanh(qv.z + kv.z) * wvv.z;
        s += fast_tanh(qv.w + kv.w) * wvv.w;
#pragma unroll
        for (int m = 1; m < 64; m <<= 1) s += __shfl_xor(s, m);
        if (lane == 0) {
            float ev = __expf(s);
            e[row * 512 + k] = ev;
            dsum += ev;
        }
    }
    if (lane == 0) wsum[w] = dsum;
    __syncthreads();
    if (tid == 0) atomicAdd(&denom[q], wsum[0] + wsum[1] + wsum[2] + wsum[3]);
}

// rep + gate + x0
__global__ void rep_gate(const float* __restrict__ e, const float* __restrict__ denom,
                         const float* __restrict__ keys, const float* __restrict__ queries,
                         const float* __restrict__ Wg, const float* __restrict__ bg,
                         float* __restrict__ x0) {
    __shared__ float att[512];
    __shared__ float urow[256];
    const int tid = threadIdx.x;
    const int row = blockIdx.x;      // b*128 + q
    const int b = row >> 7, q = row & 127;
    const float inv = 1.f / denom[q];
    att[tid] = e[row * 512 + tid] * inv;
    att[tid + 256] = e[row * 512 + 256 + tid] * inv;
    __syncthreads();
    float racc = 0.f;
#pragma unroll 4
    for (int k = 0; k < 512; ++k) racc += att[k] * keys[(b * 512 + k) * 256 + tid];
    const float u = queries[row * 256 + tid] + racc;
    urow[tid] = u;
    __syncthreads();
    const float4* uv = (const float4*)urow;
    const float4* wr = (const float4*)(Wg + tid * 256);
    float g = 0.f;
#pragma unroll 8
    for (int k4 = 0; k4 < 64; ++k4) {
        float4 a = uv[k4];
        float4 wq = wr[k4];
        g += a.x * wq.x + a.y * wq.y + a.z * wq.z + a.w * wq.w;
    }
    g += bg[tid];
    x0[row * 256 + tid] = fast_sigmoid(g) * u;
}

// Single-thread poll: tid0 spins on the flag, everyone else parks at the
// barrier; then ALL threads acquire-fence (invalidate stale L1/L2 lines).
__device__ __forceinline__ void poll_flag(const uint* cnt, uint need, int tid) {
    if (tid == 0) {
        while (atomicAdd((uint*)cnt, 0u) < need) __builtin_amdgcn_s_sleep(1);
    }
    __syncthreads();
    __threadfence();
}

// Layer-pipelined GRU (r13/r14/r18-proven): GRANULE=4 publish/poll, P-roles M=16.
// Flags padded 128B apart + single-thread poll. Roles: 0=W0 2=W1 4=W2, 1=P1 3=P2.
// Acyclic deps + full-length buffers -> deadlock-free under any scheduling.
__global__ __launch_bounds__(256, 1)
void gru_pipe(const float* __restrict__ gi0,
              float* __restrict__ gi1, float* __restrict__ gi2,
              const float* __restrict__ whh, const float* __restrict__ bhh,
              const float* __restrict__ wih, const float* __restrict__ bih,
              ushort* __restrict__ xbf0, ushort* __restrict__ xbf1,
              uint* __restrict__ flags, float* __restrict__ dout) {
    __shared__ __align__(16) ushort abuf[2][32][16][8];   // 16KB (P uses abuf[0])
    __shared__ float gibuf[2][3072];                      // 24KB (W only)
    __shared__ float gbuf[3][4][256];                     // 12KB (W only)

    const int role = blockIdx.x;
    const int tid = threadIdx.x;
    const int lane = tid & 63, w = tid >> 6;
    const int l15 = lane & 15, lhi = lane >> 4;

    // flags padded: counter i at flags[i*32] (128B apart, distinct cachelines)
    uint* f_x0 = flags + 0;    // W0 -> P1
    uint* f_g1 = flags + 32;   // P1 -> W1
    uint* f_x1 = flags + 64;   // W1 -> P2
    uint* f_g2 = flags + 96;   // P2 -> W2

    if ((role & 1) == 0) {
        // ---------------- W role: recurrence for layer l ----------------
        const int l = role >> 1;
        const float* gi    = (l == 0) ? gi0 : (l == 1) ? gi1 : gi2;  // [128][4][768]
        const float* whh_l = whh + l * 196608;
        const float* bhh_l = bhh + l * 768;
        uint* gcnt  = (l == 1) ? f_g1 : (l == 2) ? f_g2 : nullptr;
        ushort* xbf = (l == 0) ? xbf0 : (l == 1) ? xbf1 : nullptr;   // [128][4][256] bf16
        uint* xcnt  = (l == 0) ? f_x0 : (l == 1) ? f_x1 : nullptr;

        for (int i = tid; i < 8192; i += 256) ((ushort*)abuf)[i] = 0;

        short8 bf_v[4][8];
        i32x4  bf_a[8][8];
#pragma unroll
        for (int i = 0; i < 12; ++i) {
            const int g = i >> 2, c = i & 3;
            const float* basef = whh_l + (g * 256 + w * 64 + c * 16 + l15) * 256 + lhi * 8;
#pragma unroll
            for (int ks = 0; ks < 8; ++ks) {
                const float4 a0 = *(const float4*)(basef + ks * 32);
                const float4 a1 = *(const float4*)(basef + ks * 32 + 4);
                short8 v;
                v[0] = (short)f2bf(a0.x); v[1] = (short)f2bf(a0.y);
                v[2] = (short)f2bf(a0.z); v[3] = (short)f2bf(a0.w);
                v[4] = (short)f2bf(a1.x); v[5] = (short)f2bf(a1.y);
                v[6] = (short)f2bf(a1.z); v[7] = (short)f2bf(a1.w);
                if (i < 4) bf_v[i][ks] = v;
                else       bf_a[i - 4][ks] = __builtin_bit_cast(i32x4, v);
            }
        }

        const int pb_b = lhi;
        const int pb_c = (w << 6) + (l15 << 2);
        const f32x4 bn4 = *(const f32x4*)(bhh_l + 512 + pb_c);
        float hreg[4] = {0.f, 0.f, 0.f, 0.f};

        // gi row 0 preload (granule 0 poll for l1/l2)
        if (gcnt) poll_flag(gcnt, 1u, tid);
#pragma unroll
        for (int m = 0; m < 12; ++m) gibuf[0][tid + 256 * m] = gi[tid + 256 * m];
        __syncthreads();

        for (int t = 0; t < 128; ++t) {
            // async prefetch gi row t+1; poll producer only at granule boundary
            if (t < 127) {
                if (gcnt && ((t + 1) & 3) == 0)
                    poll_flag(gcnt, (uint)(((t + 1) >> 2) + 1), tid);
#pragma unroll
                for (int m = 0; m < 12; ++m) {
                    const int jw = m * 256 + (w << 6);
                    __builtin_amdgcn_global_load_lds(
                        (const __attribute__((address_space(1))) unsigned int*)(gi + (t + 1) * 3072 + jw + lane),
                        (__attribute__((address_space(3))) unsigned int*)&gibuf[(t + 1) & 1][jw],
                        4, 0, 0);
                }
            }
            // phase A: gh = h~ @ Whh^T (reads abuf[t&1], XOR-swizzled rows)
            f32x4 acc[12];
#pragma unroll
            for (int i = 0; i < 12; ++i)
#pragma unroll
                for (int cc = 0; cc < 4; ++cc) acc[i][cc] = 0.f;
#pragma unroll
            for (int ks = 0; ks < 8; ++ks) {
                const int grp = ks * 4 + lhi;
                const short8 a = *(const short8*)&abuf[t & 1][grp][l15 ^ (grp & 15)][0];
#pragma unroll
                for (int i = 0; i < 4; ++i)
                    acc[i] = __builtin_amdgcn_mfma_f32_16x16x32_bf16(a, bf_v[i][ks], acc[i], 0, 0, 0);
#pragma unroll
                for (int i = 0; i < 8; ++i)
                    asm("v_mfma_f32_16x16x32_bf16 %0, %1, %2, %0"
                        : "+v"(acc[4 + i])
                        : "v"(a), "a"(bf_a[i][ks]));
            }
            // acc -> gbuf (wave-local; same-wave LDS ordering, r10-proven)
            if (lane < 16) {
#pragma unroll
                for (int g = 0; g < 3; ++g)
#pragma unroll
                    for (int c = 0; c < 4; ++c)
#pragma unroll
                        for (int b = 0; b < 4; ++b)
                            gbuf[g][b][(w << 6) + (c << 4) + l15] = acc[g * 4 + c][b];
            }
            // phase B
            {
                const float* gcur = gibuf[t & 1];
                const f32x4 gr = *(const f32x4*)&gbuf[0][pb_b][pb_c];
                const f32x4 gz = *(const f32x4*)&gbuf[1][pb_b][pb_c];
                const f32x4 gn = *(const f32x4*)&gbuf[2][pb_b][pb_c];
                const f32x4 ir = *(const f32x4*)&gcur[pb_b * 768 + pb_c];
                const f32x4 iz = *(const f32x4*)&gcur[pb_b * 768 + 256 + pb_c];
                const f32x4 in_ = *(const f32x4*)&gcur[pb_b * 768 + 512 + pb_c];
                f32x4 xo;
                short4_t hb;
#pragma unroll
                for (int j = 0; j < 4; ++j) {
                    const float r = fast_sigmoid(ir[j] + gr[j]);
                    const float z = fast_sigmoid(iz[j] + gz[j]);
                    const float nn = fast_tanh(in_[j] + r * (gn[j] + bn4[j]));
                    const float h2 = nn + z * (hreg[j] - nn);
                    hreg[j] = h2;
                    xo[j] = h2;
                    hb[j] = (short)f2bf(h2);
                }
                if (xbf) {
                    // VOLATILE 8B store (write-through to device coherence point,
                    // r16-proven correct). Drained by the step-end syncthreads ->
                    // no release fence needed at the granule publish.
                    *(volatile u64*)&xbf[t * 1024 + pb_b * 256 + pb_c] =
                        __builtin_bit_cast(u64, hb);
                } else {
                    *(f32x4*)&dout[(pb_b * 128 + t) * 256 + pb_c] = xo;    // layer 2
                }
                const int grp = pb_c >> 3;
                *(short4_t*)&abuf[(t + 1) & 1][grp][pb_b ^ (grp & 15)][pb_c & 7] = hb;
            }
            __syncthreads();   // abuf[t+1]+gibuf[t+1] published; volatile xbf drained
            // publish once per 4-step granule — NO release fence (stores are
            // write-through and vmcnt-drained; atomicExch is device-scope)
            if (xcnt && (t & 3) == 3 && tid == 0)
                atomicExch(xcnt, (uint)((t >> 2) + 1));
        }
    } else {
        // ------- P role: gi_{pl}[4j..4j+3] = x_{pl-1}[granule j] @ Wih_pl^T + bias -------
        // M=16 (4 steps x 4 batches): logical A-row m = s*4 + b. UNCHANGED from r18.
        const int pl = (role + 1) >> 1;                 // 1 or 2
        const ushort* xbf = (pl == 1) ? xbf0 : xbf1;
        uint* xcnt  = (pl == 1) ? f_x0 : f_x1;
        float* gout = (pl == 1) ? gi1 : gi2;
        uint* gcnt  = (pl == 1) ? f_g1 : f_g2;
        const float* wih_l = wih + pl * 196608;
        const float* bih_l = bih + pl * 768;
        const float* bhh_l = bhh + pl * 768;

        short8 pf_v[4][8];
        i32x4  pf_a[8][8];
        int   n12[12];
        float b12[12];
#pragma unroll
        for (int i = 0; i < 12; ++i) {
            const int g = i >> 2, c = i & 3;
            const int n = g * 256 + w * 64 + c * 16 + l15;
            n12[i] = n;
            b12[i] = bih_l[n] + (n < 512 ? bhh_l[n] : 0.f);
            const float* basef = wih_l + n * 256 + lhi * 8;
#pragma unroll
            for (int ks = 0; ks < 8; ++ks) {
                const float4 a0 = *(const float4*)(basef + ks * 32);
                const float4 a1 = *(const float4*)(basef + ks * 32 + 4);
                short8 v;
                v[0] = (short)f2bf(a0.x); v[1] = (short)f2bf(a0.y);
                v[2] = (short)f2bf(a0.z); v[3] = (short)f2bf(a0.w);
                v[4] = (short)f2bf(a1.x); v[5] = (short)f2bf(a1.y);
                v[6] = (short)f2bf(a1.z); v[7] = (short)f2bf(a1.w);
                if (i < 4) pf_v[i][ks] = v;
                else       pf_a[i - 4][ks] = __builtin_bit_cast(i32x4, v);
            }
        }
        const int pb_c = (w << 6) + (l15 << 2);
        __syncthreads();

        for (int j = 0; j < 32; ++j) {
            poll_flag(xcnt, (uint)(j + 1), tid);
            // stage granule: thread (lhi=b, pb_c) stages rows m = s*4+lhi, s=0..3
#pragma unroll
            for (int s = 0; s < 4; ++s) {
                const short4_t xv = *(const short4_t*)&xbf[(4 * j + s) * 1024 + lhi * 256 + pb_c];
                const int m = s * 4 + lhi;
                const int grp = pb_c >> 3;
                *(short4_t*)&abuf[0][grp][m ^ (grp & 15)][pb_c & 7] = xv;
            }
            __syncthreads();
            f32x4 acc[12];
#pragma unroll
            for (int i = 0; i < 12; ++i)
#pragma unroll
                for (int cc = 0; cc < 4; ++cc) acc[i][cc] = 0.f;
#pragma unroll
            for (int ks = 0; ks < 8; ++ks) {
                const int grp = ks * 4 + lhi;
                const short8 a = *(const short8*)&abuf[0][grp][l15 ^ (grp & 15)][0];
#pragma unroll
                for (int i = 0; i < 4; ++i)
                    acc[i] = __builtin_amdgcn_mfma_f32_16x16x32_bf16(a, pf_v[i][ks], acc[i], 0, 0, 0);
#pragma unroll
                for (int i = 0; i < 8; ++i)
                    asm("v_mfma_f32_16x16x32_bf16 %0, %1, %2, %0"
                        : "+v"(acc[4 + i])
                        : "v"(a), "a"(pf_a[i][ks]));
            }
            // output: lane (lhi,l15) reg r holds row m=lhi*4+r -> t=4j+lhi, batch=r
#pragma unroll
            for (int i = 0; i < 12; ++i)
#pragma unroll
                for (int b = 0; b < 4; ++b)
                    gout[(4 * j + lhi) * 3072 + b * 768 + n12[i]] = acc[i][b] + b12[i];
            __syncthreads();   // drains gout stores + all abuf reads done
            if (tid == 0) { __threadfence(); atomicExch(gcnt, (uint)(j + 1)); }
        }
    }
}

extern "C" void kernel_launch(void* const* d_in, const int* in_sizes, int n_in,
                              void* d_out, int out_size, void* d_ws, size_t ws_size,
                              hipStream_t stream) {
    (void)in_sizes; (void)n_in; (void)out_size; (void)ws_size;
    const float* keys    = (const float*)d_in[0];
    const float* queries = (const float*)d_in[1];
    const float* W_k     = (const float*)d_in[2];
    const float* W_q     = (const float*)d_in[3];
    const float* w_v     = (const float*)d_in[4];
    const float* W_g_w   = (const float*)d_in[5];
    const float* W_g_b   = (const float*)d_in[6];
    const float* Wih     = (const float*)d_in[7];
    const float* Whh     = (const float*)d_in[8];
    const float* bih     = (const float*)d_in[9];
    const float* bhh     = (const float*)d_in[10];

    float* ws = (float*)d_ws;
    float* Kp_gi0 = ws;              // 524288 (Kp; first 393216 reused as gi0)
    float* Qp    = ws + 524288;      // 131072
    float* e     = ws + 655360;      // 262144 (dead after rep_gate; overlaid by gi1)
    float* den   = ws + 917504;      // 256
    float* xA    = ws + 917760;      // 131072 (dead after gi0 gemm)
    float* gi1   = ws + 655360;      // 393216 (overlays e+den+xA, all dead by pipe time)
    float* gi2   = ws + 1048576;     // 393216
    ushort* xbf0 = (ushort*)(ws + 1441792);  // 131072 ushort
    ushort* xbf1 = (ushort*)(ws + 1507328);  // 131072 ushort
    uint*  flags = (uint*)(ws + 1572864);    // 4 counters, 128B apart (512B total)

    hipMemsetAsync((void*)den, 0, 512, stream);
    hipMemsetAsync((void*)flags, 0, 512, stream);

    gemm_rowwise8<<<256, 256, 0, stream>>>(keys, W_k, nullptr, nullptr, Kp_gi0, 256, 0);
    gemm_rowwise8<<<64, 256, 0, stream>>>(queries, W_q, nullptr, nullptr, Qp, 256, 0);
    attn_scores<<<512, 256, 0, stream>>>(Kp_gi0, Qp, w_v, e, den);
    rep_gate<<<512, 256, 0, stream>>>(e, den, keys, queries, W_g_w, W_g_b, xA);

    float* gi0 = Kp_gi0;   // Kp dead after attn_scores
    // gi0 = x0 @ Wih0^T + bih0 + bhh0_rz, in [t][b][c] stream layout
    gemm_rowwise8<<<64, 256, 0, stream>>>(xA, Wih, bih, bhh, gi0, 768, 1);

    gru_pipe<<<5, 256, 0, stream>>>(gi0, gi1, gi2, Whh, bhh, Wih, bih,
                                    xbf0, xbf1, flags, (float*)d_out);
}

// Round 20
// 678.516 us; speedup vs baseline: 2.2944x; 1.0090x over previous
//
#include <hip/hip_runtime.h>
#include <hip/hip_bf16.h>

// Problem constants: B=4, LK=512, LQ=128, D=256, H=256, L=3
// out: x [4,128,256] float32
// ROUND 20 = r19 + ONE change: per-granule consumer ACQUIRE fences removed;
// ONE startup __threadfence per block replaces them. Rationale: every stream
// address is single-write/single-read per replay and read only after the flag,
// so first touch is a guaranteed miss that fetches from L3 (W streams: volatile
// write-through, r19; P streams: release-fence writeback, unchanged). Only
// prior-replay lines can be stale -> startup invalidate. r16 empirically
// validated the no-per-granule-acquire pattern.
// Banned: defer-store (r9 NaN), 8-wave gru (r7/r8/r11), granule>4 (r17 NaN),
// volatile scalar P-stores (r16 -245us).

typedef __attribute__((ext_vector_type(8))) short short8;
typedef __attribute__((ext_vector_type(4))) short short4_t;
typedef __attribute__((ext_vector_type(4))) float f32x4;
typedef __attribute__((ext_vector_type(4))) int i32x4;
typedef unsigned short ushort;
typedef unsigned int uint;
typedef unsigned long long u64;

__device__ __forceinline__ float fast_rcp(float x) { return __builtin_amdgcn_rcpf(x); }
__device__ __forceinline__ float fast_tanh(float x) {
    float e = __expf(2.f * x);
    return 1.f - 2.f * fast_rcp(1.f + e);
}
__device__ __forceinline__ float fast_sigmoid(float x) {
    return fast_rcp(1.f + __expf(-x));
}
__device__ __forceinline__ ushort f2bf(float v) {
    unsigned int b = __builtin_bit_cast(unsigned int, v);
    unsigned int r = (b + 0x7fffu + ((b >> 16) & 1u)) >> 16;
    return (ushort)r;
}

// 8-rows-per-block GEMM. tb=0: out[row*N+n]. tb=1 (gi stream layout): row=(b*128+t)
// is remapped to out[(t*4+b)*768+n].
__global__ void gemm_rowwise8(const float* __restrict__ in, const float* __restrict__ W,
                              const float* __restrict__ bias, const float* __restrict__ bias2,
                              float* __restrict__ out, int N, int tb) {
    __shared__ float xrow[8][256];
    const int tid = threadIdx.x;
    const int row0 = blockIdx.x * 8;
#pragma unroll
    for (int r = 0; r < 8; ++r) xrow[r][tid] = in[(row0 + r) * 256 + tid];
    __syncthreads();
    for (int n = tid; n < N; n += 256) {
        const float4* wv = (const float4*)(W + n * 256);
        float s[8] = {0.f, 0.f, 0.f, 0.f, 0.f, 0.f, 0.f, 0.f};
#pragma unroll 4
        for (int k4 = 0; k4 < 64; ++k4) {
            const float4 b = wv[k4];
#pragma unroll
            for (int r = 0; r < 8; ++r) {
                const float4 a = ((const float4*)xrow[r])[k4];   // broadcast read (free)
                s[r] += a.x * b.x + a.y * b.y + a.z * b.z + a.w * b.w;
            }
        }
        float bb = 0.f;
        if (bias) bb += bias[n];
        if (bias2 && n < 512) bb += bias2[n];
#pragma unroll
        for (int r = 0; r < 8; ++r) {
            const int row = row0 + r;
            if (tb) out[((row & 127) * 4 + (row >> 7)) * 768 + n] = s[r] + bb;
            else    out[row * N + n] = s[r] + bb;
        }
    }
}

// e[b,q,k] = exp( sum_h w_v[h]*tanh(Qp[b,q,h]+Kp[b,k,h]) ); denom[q] += sum over (b,k)
__global__ void attn_scores(const float* __restrict__ Kp, const float* __restrict__ Qp,
                            const float* __restrict__ wv, float* __restrict__ e,
                            float* __restrict__ denom) {
    __shared__ float qrow[256];
    __shared__ float wvr[256];
    __shared__ float wsum[4];
    const int tid = threadIdx.x;
    const int row = blockIdx.x;      // b*128 + q
    const int b = row >> 7, q = row & 127;
    qrow[tid] = Qp[row * 256 + tid];
    wvr[tid] = wv[tid];
    __syncthreads();
    const int lane = tid & 63, w = tid >> 6;
    const float4 qv = ((const float4*)qrow)[lane];
    const float4 wvv = ((const float4*)wvr)[lane];
    float dsum = 0.f;
    for (int k = w; k < 512; k += 4) {
        const float4 kv = *(const float4*)(Kp + (b * 512 + k) * 256 + lane * 4);
        float s = fast_tanh(qv.x + kv.x) * wvv.x;
        s += fast_tanh(qv.y + kv.y) * wvv.y;
        s += fast_tanh(qv.z + kv.z) * wvv.z;
        s += fast_tanh(qv.w + kv.w) * wvv.w;
#pragma unroll
        for (int m = 1; m < 64; m <<= 1) s += __shfl_xor(s, m);
        if (lane == 0) {
            float ev = __expf(s);
            e[row * 512 + k] = ev;
            dsum += ev;
        }
    }
    if (lane == 0) wsum[w] = dsum;
    __syncthreads();
    if (tid == 0) atomicAdd(&denom[q], wsum[0] + wsum[1] + wsum[2] + wsum[3]);
}

// rep + gate + x0
__global__ void rep_gate(const float* __restrict__ e, const float* __restrict__ denom,
                         const float* __restrict__ keys, const float* __restrict__ queries,
                         const float* __restrict__ Wg, const float* __restrict__ bg,
                         float* __restrict__ x0) {
    __shared__ float att[512];
    __shared__ float urow[256];
    const int tid = threadIdx.x;
    const int row = blockIdx.x;      // b*128 + q
    const int b = row >> 7, q = row & 127;
    const float inv = 1.f / denom[q];
    att[tid] = e[row * 512 + tid] * inv;
    att[tid + 256] = e[row * 512 + 256 + tid] * inv;
    __syncthreads();
    float racc = 0.f;
#pragma unroll 4
    for (int k = 0; k < 512; ++k) racc += att[k] * keys[(b * 512 + k) * 256 + tid];
    const float u = queries[row * 256 + tid] + racc;
    urow[tid] = u;
    __syncthreads();
    const float4* uv = (const float4*)urow;
    const float4* wr = (const float4*)(Wg + tid * 256);
    float g = 0.f;
#pragma unroll 8
    for (int k4 = 0; k4 < 64; ++k4) {
        float4 a = uv[k4];
        float4 wq = wr[k4];
        g += a.x * wq.x + a.y * wq.y + a.z * wq.z + a.w * wq.w;
    }
    g += bg[tid];
    x0[row * 256 + tid] = fast_sigmoid(g) * u;
}

// Fence-free poll (this round): tid0 spins on the device-scope atomic, others
// park at the barrier. No per-granule acquire fence — staleness is impossible
// for single-read-after-flag streams once the startup fence has dropped
// prior-replay lines (r16-validated pattern).
__device__ __forceinline__ void poll_flag(const uint* cnt, uint need, int tid) {
    if (tid == 0) {
        while (atomicAdd((uint*)cnt, 0u) < need) __builtin_amdgcn_s_sleep(1);
    }
    __syncthreads();
}

// Layer-pipelined GRU (r13/r14/r18/r19-proven core): GRANULE=4 publish/poll,
// P-roles M=16. Flags padded 128B apart + single-thread poll. Roles:
// 0=W0 2=W1 4=W2 (recurrence, volatile 8B xbf publication), 1=P1 3=P2
// (projection, normal stores + release fence). Acyclic deps + full-length
// buffers -> deadlock-free under any scheduling.
__global__ __launch_bounds__(256, 1)
void gru_pipe(const float* __restrict__ gi0,
              float* __restrict__ gi1, float* __restrict__ gi2,
              const float* __restrict__ whh, const float* __restrict__ bhh,
              const float* __restrict__ wih, const float* __restrict__ bih,
              ushort* __restrict__ xbf0, ushort* __restrict__ xbf1,
              uint* __restrict__ flags, float* __restrict__ dout) {
    __shared__ __align__(16) ushort abuf[2][32][16][8];   // 16KB (P uses abuf[0])
    __shared__ float gibuf[2][3072];                      // 24KB (W only)
    __shared__ float gbuf[3][4][256];                     // 12KB (W only)

    const int role = blockIdx.x;
    const int tid = threadIdx.x;
    const int lane = tid & 63, w = tid >> 6;
    const int l15 = lane & 15, lhi = lane >> 4;

    // ONE startup fence: drop any L1/L2 line cached during a previous graph
    // replay. After this, every stream address is first-touch-after-flag ->
    // guaranteed fetch from the coherence point.
    __threadfence();

    // flags padded: counter i at flags[i*32] (128B apart, distinct cachelines)
    uint* f_x0 = flags + 0;    // W0 -> P1
    uint* f_g1 = flags + 32;   // P1 -> W1
    uint* f_x1 = flags + 64;   // W1 -> P2
    uint* f_g2 = flags + 96;   // P2 -> W2

    if ((role & 1) == 0) {
        // ---------------- W role: recurrence for layer l ----------------
        const int l = role >> 1;
        const float* gi    = (l == 0) ? gi0 : (l == 1) ? gi1 : gi2;  // [128][4][768]
        const float* whh_l = whh + l * 196608;
        const float* bhh_l = bhh + l * 768;
        uint* gcnt  = (l == 1) ? f_g1 : (l == 2) ? f_g2 : nullptr;
        ushort* xbf = (l == 0) ? xbf0 : (l == 1) ? xbf1 : nullptr;   // [128][4][256] bf16
        uint* xcnt  = (l == 0) ? f_x0 : (l == 1) ? f_x1 : nullptr;

        for (int i = tid; i < 8192; i += 256) ((ushort*)abuf)[i] = 0;

        short8 bf_v[4][8];
        i32x4  bf_a[8][8];
#pragma unroll
        for (int i = 0; i < 12; ++i) {
            const int g = i >> 2, c = i & 3;
            const float* basef = whh_l + (g * 256 + w * 64 + c * 16 + l15) * 256 + lhi * 8;
#pragma unroll
            for (int ks = 0; ks < 8; ++ks) {
                const float4 a0 = *(const float4*)(basef + ks * 32);
                const float4 a1 = *(const float4*)(basef + ks * 32 + 4);
                short8 v;
                v[0] = (short)f2bf(a0.x); v[1] = (short)f2bf(a0.y);
                v[2] = (short)f2bf(a0.z); v[3] = (short)f2bf(a0.w);
                v[4] = (short)f2bf(a1.x); v[5] = (short)f2bf(a1.y);
                v[6] = (short)f2bf(a1.z); v[7] = (short)f2bf(a1.w);
                if (i < 4) bf_v[i][ks] = v;
                else       bf_a[i - 4][ks] = __builtin_bit_cast(i32x4, v);
            }
        }

        const int pb_b = lhi;
        const int pb_c = (w << 6) + (l15 << 2);
        const f32x4 bn4 = *(const f32x4*)(bhh_l + 512 + pb_c);
        float hreg[4] = {0.f, 0.f, 0.f, 0.f};

        // gi row 0 preload (granule 0 poll for l1/l2)
        if (gcnt) poll_flag(gcnt, 1u, tid);
#pragma unroll
        for (int m = 0; m < 12; ++m) gibuf[0][tid + 256 * m] = gi[tid + 256 * m];
        __syncthreads();

        for (int t = 0; t < 128; ++t) {
            // async prefetch gi row t+1; poll producer only at granule boundary
            if (t < 127) {
                if (gcnt && ((t + 1) & 3) == 0)
                    poll_flag(gcnt, (uint)(((t + 1) >> 2) + 1), tid);
#pragma unroll
                for (int m = 0; m < 12; ++m) {
                    const int jw = m * 256 + (w << 6);
                    __builtin_amdgcn_global_load_lds(
                        (const __attribute__((address_space(1))) unsigned int*)(gi + (t + 1) * 3072 + jw + lane),
                        (__attribute__((address_space(3))) unsigned int*)&gibuf[(t + 1) & 1][jw],
                        4, 0, 0);
                }
            }
            // phase A: gh = h~ @ Whh^T (reads abuf[t&1], XOR-swizzled rows)
            f32x4 acc[12];
#pragma unroll
            for (int i = 0; i < 12; ++i)
#pragma unroll
                for (int cc = 0; cc < 4; ++cc) acc[i][cc] = 0.f;
#pragma unroll
            for (int ks = 0; ks < 8; ++ks) {
                const int grp = ks * 4 + lhi;
                const short8 a = *(const short8*)&abuf[t & 1][grp][l15 ^ (grp & 15)][0];
#pragma unroll
                for (int i = 0; i < 4; ++i)
                    acc[i] = __builtin_amdgcn_mfma_f32_16x16x32_bf16(a, bf_v[i][ks], acc[i], 0, 0, 0);
#pragma unroll
                for (int i = 0; i < 8; ++i)
                    asm("v_mfma_f32_16x16x32_bf16 %0, %1, %2, %0"
                        : "+v"(acc[4 + i])
                        : "v"(a), "a"(bf_a[i][ks]));
            }
            // acc -> gbuf (wave-local; same-wave LDS ordering, r10-proven)
            if (lane < 16) {
#pragma unroll
                for (int g = 0; g < 3; ++g)
#pragma unroll
                    for (int c = 0; c < 4; ++c)
#pragma unroll
                        for (int b = 0; b < 4; ++b)
                            gbuf[g][b][(w << 6) + (c << 4) + l15] = acc[g * 4 + c][b];
            }
            // phase B
            {
                const float* gcur = gibuf[t & 1];
                const f32x4 gr = *(const f32x4*)&gbuf[0][pb_b][pb_c];
                const f32x4 gz = *(const f32x4*)&gbuf[1][pb_b][pb_c];
                const f32x4 gn = *(const f32x4*)&gbuf[2][pb_b][pb_c];
                const f32x4 ir = *(const f32x4*)&gcur[pb_b * 768 + pb_c];
                const f32x4 iz = *(const f32x4*)&gcur[pb_b * 768 + 256 + pb_c];
                const f32x4 in_ = *(const f32x4*)&gcur[pb_b * 768 + 512 + pb_c];
                f32x4 xo;
                short4_t hb;
#pragma unroll
                for (int j = 0; j < 4; ++j) {
                    const float r = fast_sigmoid(ir[j] + gr[j]);
                    const float z = fast_sigmoid(iz[j] + gz[j]);
                    const float nn = fast_tanh(in_[j] + r * (gn[j] + bn4[j]));
                    const float h2 = nn + z * (hreg[j] - nn);
                    hreg[j] = h2;
                    xo[j] = h2;
                    hb[j] = (short)f2bf(h2);
                }
                if (xbf) {
                    // VOLATILE 8B store (write-through to device coherence point,
                    // r16/r19-proven). Drained by the step-end syncthreads.
                    *(volatile u64*)&xbf[t * 1024 + pb_b * 256 + pb_c] =
                        __builtin_bit_cast(u64, hb);
                } else {
                    *(f32x4*)&dout[(pb_b * 128 + t) * 256 + pb_c] = xo;    // layer 2
                }
                const int grp = pb_c >> 3;
                *(short4_t*)&abuf[(t + 1) & 1][grp][pb_b ^ (grp & 15)][pb_c & 7] = hb;
            }
            __syncthreads();   // abuf[t+1]+gibuf[t+1] published; volatile xbf drained
            // publish once per 4-step granule — no release fence (write-through)
            if (xcnt && (t & 3) == 3 && tid == 0)
                atomicExch(xcnt, (uint)((t >> 2) + 1));
        }
    } else {
        // ------- P role: gi_{pl}[4j..4j+3] = x_{pl-1}[granule j] @ Wih_pl^T + bias -------
        // M=16 (4 steps x 4 batches): logical A-row m = s*4 + b. Normal stores +
        // release fence (unchanged; volatile scalar stores banned per r16).
        const int pl = (role + 1) >> 1;                 // 1 or 2
        const ushort* xbf = (pl == 1) ? xbf0 : xbf1;
        uint* xcnt  = (pl == 1) ? f_x0 : f_x1;
        float* gout = (pl == 1) ? gi1 : gi2;
        uint* gcnt  = (pl == 1) ? f_g1 : f_g2;
        const float* wih_l = wih + pl * 196608;
        const float* bih_l = bih + pl * 768;
        const float* bhh_l = bhh + pl * 768;

        short8 pf_v[4][8];
        i32x4  pf_a[8][8];
        int   n12[12];
        float b12[12];
#pragma unroll
        for (int i = 0; i < 12; ++i) {
            const int g = i >> 2, c = i & 3;
            const int n = g * 256 + w * 64 + c * 16 + l15;
            n12[i] = n;
            b12[i] = bih_l[n] + (n < 512 ? bhh_l[n] : 0.f);
            const float* basef = wih_l + n * 256 + lhi * 8;
#pragma unroll
            for (int ks = 0; ks < 8; ++ks) {
                const float4 a0 = *(const float4*)(basef + ks * 32);
                const float4 a1 = *(const float4*)(basef + ks * 32 + 4);
                short8 v;
                v[0] = (short)f2bf(a0.x); v[1] = (short)f2bf(a0.y);
                v[2] = (short)f2bf(a0.z); v[3] = (short)f2bf(a0.w);
                v[4] = (short)f2bf(a1.x); v[5] = (short)f2bf(a1.y);
                v[6] = (short)f2bf(a1.z); v[7] = (short)f2bf(a1.w);
                if (i < 4) pf_v[i][ks] = v;
                else       pf_a[i - 4][ks] = __builtin_bit_cast(i32x4, v);
            }
        }
        const int pb_c = (w << 6) + (l15 << 2);
        __syncthreads();

        for (int j = 0; j < 32; ++j) {
            poll_flag(xcnt, (uint)(j + 1), tid);
            // stage granule: thread (lhi=b, pb_c) stages rows m = s*4+lhi, s=0..3
#pragma unroll
            for (int s = 0; s < 4; ++s) {
                const short4_t xv = *(const short4_t*)&xbf[(4 * j + s) * 1024 + lhi * 256 + pb_c];
                const int m = s * 4 + lhi;
                const int grp = pb_c >> 3;
                *(short4_t*)&abuf[0][grp][m ^ (grp & 15)][pb_c & 7] = xv;
            }
            __syncthreads();
            f32x4 acc[12];
#pragma unroll
            for (int i = 0; i < 12; ++i)
#pragma unroll
                for (int cc = 0; cc < 4; ++cc) acc[i][cc] = 0.f;
#pragma unroll
            for (int ks = 0; ks < 8; ++ks) {
                const int grp = ks * 4 + lhi;
                const short8 a = *(const short8*)&abuf[0][grp][l15 ^ (grp & 15)][0];
#pragma unroll
                for (int i = 0; i < 4; ++i)
                    acc[i] = __builtin_amdgcn_mfma_f32_16x16x32_bf16(a, pf_v[i][ks], acc[i], 0, 0, 0);
#pragma unroll
                for (int i = 0; i < 8; ++i)
                    asm("v_mfma_f32_16x16x32_bf16 %0, %1, %2, %0"
                        : "+v"(acc[4 + i])
                        : "v"(a), "a"(pf_a[i][ks]));
            }
            // output: lane (lhi,l15) reg r holds row m=lhi*4+r -> t=4j+lhi, batch=r
#pragma unroll
            for (int i = 0; i < 12; ++i)
#pragma unroll
                for (int b = 0; b < 4; ++b)
                    gout[(4 * j + lhi) * 3072 + b * 768 + n12[i]] = acc[i][b] + b12[i];
            __syncthreads();   // drains gout stores + all abuf reads done
            if (tid == 0) { __threadfence(); atomicExch(gcnt, (uint)(j + 1)); }
        }
    }
}

extern "C" void kernel_launch(void* const* d_in, const int* in_sizes, int n_in,
                              void* d_out, int out_size, void* d_ws, size_t ws_size,
                              hipStream_t stream) {
    (void)in_sizes; (void)n_in; (void)out_size; (void)ws_size;
    const float* keys    = (const float*)d_in[0];
    const float* queries = (const float*)d_in[1];
    const float* W_k     = (const float*)d_in[2];
    const float* W_q     = (const float*)d_in[3];
    const float* w_v     = (const float*)d_in[4];
    const float* W_g_w   = (const float*)d_in[5];
    const float* W_g_b   = (const float*)d_in[6];
    const float* Wih     = (const float*)d_in[7];
    const float* Whh     = (const float*)d_in[8];
    const float* bih     = (const float*)d_in[9];
    const float* bhh     = (const float*)d_in[10];

    float* ws = (float*)d_ws;
    float* Kp_gi0 = ws;              // 524288 (Kp; first 393216 reused as gi0)
    float* Qp    = ws + 524288;      // 131072
    float* e     = ws + 655360;      // 262144 (dead after rep_gate; overlaid by gi1)
    float* den   = ws + 917504;      // 256
    float* xA    = ws + 917760;      // 131072 (dead after gi0 gemm)
    float* gi1   = ws + 655360;      // 393216 (overlays e+den+xA, all dead by pipe time)
    float* gi2   = ws + 1048576;     // 393216
    ushort* xbf0 = (ushort*)(ws + 1441792);  // 131072 ushort
    ushort* xbf1 = (ushort*)(ws + 1507328);  // 131072 ushort
    uint*  flags = (uint*)(ws + 1572864);    // 4 counters, 128B apart (512B total)

    hipMemsetAsync((void*)den, 0, 512, stream);
    hipMemsetAsync((void*)flags, 0, 512, stream);

    gemm_rowwise8<<<256, 256, 0, stream>>>(keys, W_k, nullptr, nullptr, Kp_gi0, 256, 0);
    gemm_rowwise8<<<64, 256, 0, stream>>>(queries, W_q, nullptr, nullptr, Qp, 256, 0);
    attn_scores<<<512, 256, 0, stream>>>(Kp_gi0, Qp, w_v, e, den);
    rep_gate<<<512, 256, 0, stream>>>(e, den, keys, queries, W_g_w, W_g_b, xA);

    float* gi0 = Kp_gi0;   // Kp dead after attn_scores
    // gi0 = x0 @ Wih0^T + bih0 + bhh0_rz, in [t][b][c] stream layout
    gemm_rowwise8<<<64, 256, 0, stream>>>(xA, Wih, bih, bhh, gi0, 768, 1);

    gru_pipe<<<5, 256, 0, stream>>>(gi0, gi1, gi2, Whh, bhh, Wih, bih,
                                    xbf0, xbf1, flags, (float*)d_out);
}